// Round 1
// baseline (811.405 us; speedup 1.0000x reference)
//
#include <hip/hip_runtime.h>

// ---------------------------------------------------------------------------
// WindowedSelfAttention: N=4, S=2048, E=512, H=8, D=64, WIN=256
// out  : [N,S,E] f32            (d_out[0 .. 4194304))
// att  : [N,H,S,S] f32          (d_out[4194304 .. 138412032))
// Key structure: outside the +-128 window every attention entry of a row is
// the SAME constant c = exp(-m)/denom (reference zero-fills logits outside
// the band before softmax). So: compute band via MFMA, bulk-fill the rest.
// ---------------------------------------------------------------------------

typedef unsigned short u16;
typedef __bf16 bf16x8 __attribute__((ext_vector_type(8)));
typedef float  f32x4  __attribute__((ext_vector_type(4)));
typedef u16    u16x8  __attribute__((ext_vector_type(8)));

__device__ __forceinline__ u16 f2bf(float f) {
    union { float f; unsigned u; } x; x.f = f;
    unsigned u = x.u;
    u += 0x7fffu + ((u >> 16) & 1u);   // round-to-nearest-even
    return (u16)(u >> 16);
}
__device__ __forceinline__ float bf2f(u16 b) {
    union { unsigned u; float f; } x; x.u = ((unsigned)b) << 16;
    return x.f;
}
// swizzled 16B-chunk index (XOR low 3 bits; clamp for non-pow2 chunk counts)
__device__ __forceinline__ int swzc(int c, int r) {
    return (c < 32) ? (c ^ (r & 7)) : c;
}

// ---------------------------------------------------------------------------
// f32 -> bf16 conversion for 7 tensors in one launch (grid.y selects tensor)
// ---------------------------------------------------------------------------
struct CvtArgs {
    const float* src[7];
    u16*         dst[7];
    int          n[7];
};

__global__ __launch_bounds__(256) void cvt_kernel(CvtArgs a) {
    int t = blockIdx.y;
    int i = (blockIdx.x * 256 + threadIdx.x) * 4;
    if (i >= a.n[t]) return;
    float4 v = *(const float4*)(a.src[t] + i);
    ushort4 o;
    o.x = f2bf(v.x); o.y = f2bf(v.y); o.z = f2bf(v.z); o.w = f2bf(v.w);
    *(ushort4*)(a.dst[t] + i) = o;
}

// ---------------------------------------------------------------------------
// bf16 GEMM:  Y[M,512] = X[M,512] @ W[512,512]^T + bias   (W row-major [out,in])
// 128x128 tile, BK=32, 256 threads = 4 waves (2x2), each wave 64x64 (4x4 frags)
// LDS stride padded to 40 elems (80B) -> ~2-way bank conflicts on ds_read_b128.
// ---------------------------------------------------------------------------
template <bool BF16OUT>
__device__ __forceinline__ void gemm_core(const u16* __restrict__ A,
                                          const u16* __restrict__ W,
                                          const float* __restrict__ bias,
                                          void* __restrict__ outp) {
    __shared__ u16 As[128 * 40];
    __shared__ u16 Bs[128 * 40];

    const int tid  = threadIdx.x;
    const int lane = tid & 63;
    const int w    = tid >> 6;
    const int bm   = blockIdx.x, bn = blockIdx.y;
    const int wm   = w >> 1, wn = w & 1;

    f32x4 acc[4][4];
#pragma unroll
    for (int m = 0; m < 4; ++m)
#pragma unroll
        for (int n = 0; n < 4; ++n) acc[m][n] = 0;

    const size_t arow = (size_t)bm * 128 * 512;
    const size_t brow = (size_t)bn * 128 * 512;

    for (int k0 = 0; k0 < 512; k0 += 32) {
        __syncthreads();
#pragma unroll
        for (int p = 0; p < 2; ++p) {
            int idx = p * 256 + tid;
            int rr = idx >> 2, cc = idx & 3;
            *(uint4*)(&As[rr * 40 + cc * 8]) =
                *(const uint4*)(A + arow + (size_t)rr * 512 + k0 + cc * 8);
            *(uint4*)(&Bs[rr * 40 + cc * 8]) =
                *(const uint4*)(W + brow + (size_t)rr * 512 + k0 + cc * 8);
        }
        __syncthreads();

        bf16x8 af[4], bf[4];
#pragma unroll
        for (int m = 0; m < 4; ++m)
            af[m] = *(const bf16x8*)(&As[(wm * 64 + m * 16 + (lane & 15)) * 40 + (lane >> 4) * 8]);
#pragma unroll
        for (int n = 0; n < 4; ++n)
            bf[n] = *(const bf16x8*)(&Bs[(wn * 64 + n * 16 + (lane & 15)) * 40 + (lane >> 4) * 8]);
#pragma unroll
        for (int m = 0; m < 4; ++m)
#pragma unroll
            for (int n = 0; n < 4; ++n)
                acc[m][n] = __builtin_amdgcn_mfma_f32_16x16x32_bf16(af[m], bf[n], acc[m][n], 0, 0, 0);
    }

    // epilogue: C/D layout col=lane&15, row=(lane>>4)*4+reg  [m89-verified]
#pragma unroll
    for (int m = 0; m < 4; ++m) {
#pragma unroll
        for (int n = 0; n < 4; ++n) {
            int col = bn * 128 + wn * 64 + n * 16 + (lane & 15);
            float b = bias[col];
#pragma unroll
            for (int reg = 0; reg < 4; ++reg) {
                int row = bm * 128 + wm * 64 + m * 16 + (lane >> 4) * 4 + reg;
                float v = acc[m][n][reg] + b;
                if (BF16OUT)
                    ((u16*)outp)[(size_t)row * 512 + col] = f2bf(v);
                else
                    ((float*)outp)[(size_t)row * 512 + col] = v;
            }
        }
    }
}

__global__ __launch_bounds__(256) void gemm_qkv_kernel(
    const u16* xq, const u16* xk, const u16* xv,
    const u16* wq, const u16* wk, const u16* wv,
    const float* bq, const float* bk, const float* bv,
    u16* oq, u16* ok, u16* ov) {
    int z = blockIdx.z;
    const u16* A = (z == 0) ? xq : (z == 1) ? xk : xv;
    const u16* W = (z == 0) ? wq : (z == 1) ? wk : wv;
    const float* b = (z == 0) ? bq : (z == 1) ? bk : bv;
    u16* o = (z == 0) ? oq : (z == 1) ? ok : ov;
    gemm_core<true>(A, W, b, o);
}

__global__ __launch_bounds__(256) void gemm_out_kernel(
    const u16* A, const u16* W, const float* b, float* o) {
    gemm_core<false>(A, W, b, o);
}

// ---------------------------------------------------------------------------
// sumv[n,h,d] = sum_s v[n,s,h,d]   (needed for the constant-c PV correction)
// ---------------------------------------------------------------------------
__global__ __launch_bounds__(256) void sumv_kernel(const u16* __restrict__ vb,
                                                   float* __restrict__ sumv) {
    __shared__ float part[4][64];
    int nh = blockIdx.x;            // 0..31
    int n = nh >> 3, h = nh & 7;
    int tid = threadIdx.x;
    int d = tid & 63, p = tid >> 6;
    size_t base = (size_t)n * 2048 * 512 + h * 64;
    float acc = 0.f;
    for (int s = p; s < 2048; s += 4)
        acc += bf2f(vb[base + (size_t)s * 512 + d]);
    part[p][d] = acc;
    __syncthreads();
    if (tid < 64)
        sumv[(size_t)nh * 64 + tid] = part[0][tid] + part[1][tid] + part[2][tid] + part[3][tid];
}

// ---------------------------------------------------------------------------
// Fused windowed attention. One block = 32 query rows of one (n,h).
// Union of windows for 32 rows = 288 key slots starting at jlo = max(0,i0-128).
// Phases: stage Q/K/V^T -> MFMA scores -> shfl softmax stats -> write band
// attention + build A' = (att - c) in LDS -> MFMA PV -> c-fill the rest.
// LDS: Qs 4KB (aliased by stats) | Ks 36KB (aliased by A') | Vt 36KB = 76KB
// -> 2 blocks/CU.
// ---------------------------------------------------------------------------
__global__ __launch_bounds__(256) void attn_kernel(
    const u16* __restrict__ qb, const u16* __restrict__ kb,
    const u16* __restrict__ vb, const int* __restrict__ mask,
    const float* __restrict__ sumv, float* __restrict__ att,
    u16* __restrict__ oh) {
    __shared__ __attribute__((aligned(16))) char lds[77824];
    u16*   Qs      = (u16*)lds;            // [32][64] bf16, chunk-swizzled
    float* stat_m  = (float*)lds;          // [32]  (aliases Qs after scores)
    float* stat_rd = (float*)(lds + 128);  // [32]
    float* stat_c  = (float*)(lds + 256);  // [32]
    float* red     = (float*)(lds + 384);  // [4][16]
    float* red2    = (float*)(lds + 640);  // [4][16]
    u16*   Ks      = (u16*)(lds + 4096);   // [288][64] bf16, chunk-swizzled
    u16*   Ab      = Ks;                   // [32][288] bf16 (after scores)
    u16*   Vt      = (u16*)(lds + 4096 + 36864); // [64][288] bf16 transposed

    const int tid  = threadIdx.x;
    const int lane = tid & 63;
    const int w    = tid >> 6;
    const int bid  = blockIdx.x;
    const int tile = bid & 63;
    const int h    = (bid >> 6) & 7;
    const int n    = bid >> 9;
    const int i0   = tile * 32;
    const int jlo  = max(0, i0 - 128);
    const float scale = 0.04419417382415922f;  // 1/sqrt(512)

    const size_t base_nh = (size_t)n * 2048 * 512 + h * 64;

    // ---- stage Qs [32][64] ----
    {
        int r = tid >> 3, ch = tid & 7;
        uint4 v = *(const uint4*)(qb + base_nh + (size_t)(i0 + r) * 512 + ch * 8);
        *(uint4*)((char*)Qs + r * 128 + ((ch ^ (r & 7)) << 4)) = v;
    }
    // ---- stage Ks [288][64] (zero-fill j >= 2048) ----
    for (int p = 0; p < 9; ++p) {
        int idx = p * 256 + tid;
        int jj = idx >> 3, ch = idx & 7;
        int j = jlo + jj;
        uint4 v = make_uint4(0, 0, 0, 0);
        if (j < 2048) v = *(const uint4*)(kb + base_nh + (size_t)j * 512 + ch * 8);
        *(uint4*)((char*)Ks + jj * 128 + ((ch ^ (jj & 7)) << 4)) = v;
    }
    // ---- stage Vt [64][288] = V^T (coalesced 128B row reads, b128 LDS writes) ----
    {
        int d = tid & 63;
        for (int p = 0; p < 9; ++p) {
            int jc = p * 4 + w;     // chunk 0..35
            int j0 = jc * 8;
            u16x8 tmp;
#pragma unroll
            for (int r = 0; r < 8; ++r) {
                int j = jlo + j0 + r;
                tmp[r] = (j < 2048) ? vb[base_nh + (size_t)j * 512 + d] : (u16)0;
            }
            *(u16x8*)((char*)Vt + d * 576 + (swzc(jc, d) << 4)) = tmp;
        }
    }
    __syncthreads();

    // ---- scores: S[32][288] = Q . K^T, wave -> 16 rows x 144 cols ----
    const int rbase = (w & 1) * 16;
    const int cbase = (w >> 1) * 144;
    f32x4 acc[9];
#pragma unroll
    for (int f = 0; f < 9; ++f) acc[f] = 0;

    bf16x8 aq[2];
    {
        int r = rbase + (lane & 15);
#pragma unroll
        for (int ks = 0; ks < 2; ++ks) {
            int kc = ks * 4 + (lane >> 4);
            aq[ks] = *(const bf16x8*)((char*)Qs + r * 128 + ((kc ^ (r & 7)) << 4));
        }
    }
#pragma unroll
    for (int f = 0; f < 9; ++f) {
        int jj = cbase + f * 16 + (lane & 15);
#pragma unroll
        for (int ks = 0; ks < 2; ++ks) {
            int kc = ks * 4 + (lane >> 4);
            bf16x8 bk_ = *(const bf16x8*)((char*)Ks + jj * 128 + ((kc ^ (jj & 7)) << 4));
            acc[f] = __builtin_amdgcn_mfma_f32_16x16x32_bf16(aq[ks], bk_, acc[f], 0, 0, 0);
        }
    }
    __syncthreads();   // all Qs/Ks reads done; stats/A' may now alias them

    // ---- pass 1: logits + per-row max (shfl-reduce over 16-lane col group) ----
    const int rowg = (lane >> 4) * 4;
    f32x4 lv[9];
    float mx[4] = {-__builtin_inff(), -__builtin_inff(), -__builtin_inff(), -__builtin_inff()};
#pragma unroll
    for (int f = 0; f < 9; ++f) {
        int jj = cbase + f * 16 + (lane & 15);
        int j = jlo + jj;
        int mk = (j < 2048) ? mask[n * 2048 + j] : 0;
#pragma unroll
        for (int reg = 0; reg < 4; ++reg) {
            int i = i0 + rbase + rowg + reg;
            bool inw = (j >= i - 128) && (j <= i + 128) && (j < 2048);
            float val = (inw && mk != 0) ? acc[f][reg] * scale : -__builtin_inff();
            lv[f][reg] = val;
            mx[reg] = fmaxf(mx[reg], val);
        }
    }
#pragma unroll
    for (int mskk = 1; mskk < 16; mskk <<= 1)
#pragma unroll
        for (int reg = 0; reg < 4; ++reg)
            mx[reg] = fmaxf(mx[reg], __shfl_xor(mx[reg], mskk, 64));
    if ((lane & 15) == 0) {
#pragma unroll
        for (int reg = 0; reg < 4; ++reg) red[w * 16 + rowg + reg] = mx[reg];
    }
    __syncthreads();
    if (tid < 32) {
        int r = tid;
        int wa = (r < 16) ? 0 : 1, rr = r & 15;
        // outside-window logits are 0 and always present -> include 0 in max
        stat_m[r] = fmaxf(fmaxf(red[wa * 16 + rr], red[(wa + 2) * 16 + rr]), 0.0f);
    }
    __syncthreads();

    // ---- pass 2: denom ----
    float m4[4];
#pragma unroll
    for (int reg = 0; reg < 4; ++reg) m4[reg] = stat_m[rbase + rowg + reg];
    float sm[4] = {0, 0, 0, 0};
#pragma unroll
    for (int f = 0; f < 9; ++f)
#pragma unroll
        for (int reg = 0; reg < 4; ++reg)
            sm[reg] += __expf(lv[f][reg] - m4[reg]);   // -inf -> 0
#pragma unroll
    for (int mskk = 1; mskk < 16; mskk <<= 1)
#pragma unroll
        for (int reg = 0; reg < 4; ++reg)
            sm[reg] += __shfl_xor(sm[reg], mskk, 64);
    if ((lane & 15) == 0) {
#pragma unroll
        for (int reg = 0; reg < 4; ++reg) red2[w * 16 + rowg + reg] = sm[reg];
    }
    __syncthreads();
    if (tid < 32) {
        int r = tid, gi = i0 + r;
        int wa = (r < 16) ? 0 : 1, rr = r & 15;
        float s = red2[wa * 16 + rr] + red2[(wa + 2) * 16 + rr];
        int lo = max(0, gi - 128), hi = min(2048, gi + 129);
        float em = __expf(-stat_m[r]);
        float denom = s + (float)(2048 - (hi - lo)) * em;
        float rd = 1.0f / denom;
        stat_rd[r] = rd;
        stat_c[r] = em * rd;
    }
    __syncthreads();

    // ---- pass 3: write band attention + build A' = (att - c) bf16 in LDS ----
    float rd4[4], c4[4];
#pragma unroll
    for (int reg = 0; reg < 4; ++reg) {
        rd4[reg] = stat_rd[rbase + rowg + reg];
        c4[reg] = stat_c[rbase + rowg + reg];
    }
#pragma unroll
    for (int f = 0; f < 9; ++f) {
        int jj = cbase + f * 16 + (lane & 15);
        int j = jlo + jj;
        int jc = jj >> 3;
#pragma unroll
        for (int reg = 0; reg < 4; ++reg) {
            int it = rbase + rowg + reg;
            int i = i0 + it;
            bool inw = (j >= i - 128) && (j <= i + 128) && (j < 2048);
            float e = __expf(lv[f][reg] - m4[reg]);        // 0 if masked / -inf
            float a = inw ? e * rd4[reg] : c4[reg];
            if (j < 2048)
                att[((size_t)(n * 8 + h) * 2048 + i) * 2048 + j] = a;
            float ab = inw ? (a - c4[reg]) : 0.0f;
            ((u16*)((char*)Ab + it * 576 + (swzc(jc, it) << 4)))[jj & 7] = f2bf(ab);
        }
    }
    __syncthreads();

    // ---- PV: out[32][64] = A'[32][288] @ V[288][64] (via Vt), + c*sumv ----
    const int rb2 = (w & 1) * 16;
    const int db  = (w >> 1) * 32;
    f32x4 po[2];
    po[0] = 0; po[1] = 0;
#pragma unroll
    for (int ks = 0; ks < 9; ++ks) {
        int kc = ks * 4 + (lane >> 4);
        int it = rb2 + (lane & 15);
        bf16x8 af = *(const bf16x8*)((char*)Ab + it * 576 + (swzc(kc, it) << 4));
#pragma unroll
        for (int f = 0; f < 2; ++f) {
            int d = db + f * 16 + (lane & 15);
            bf16x8 bv_ = *(const bf16x8*)((char*)Vt + d * 576 + (swzc(kc, d) << 4));
            po[f] = __builtin_amdgcn_mfma_f32_16x16x32_bf16(af, bv_, po[f], 0, 0, 0);
        }
    }
    {
        const float* svp = sumv + (size_t)(n * 8 + h) * 64;
#pragma unroll
        for (int f = 0; f < 2; ++f) {
            int d = db + f * 16 + (lane & 15);
            float sv = svp[d];
#pragma unroll
            for (int reg = 0; reg < 4; ++reg) {
                int it = rb2 + rowg + reg;
                float val = po[f][reg] + stat_c[it] * sv;
                oh[base_nh + (size_t)(i0 + it) * 512 + d] = f2bf(val);
            }
        }
    }

    // ---- fill: everything outside the union gets the row constant c ----
    {
        int jend = min(2048, jlo + 288);
        int j4lo = jlo >> 2, j4end = jend >> 2;
        for (int idx = tid; idx < 32 * 512; idx += 256) {
            int r = idx >> 9;
            int j4 = idx & 511;
            if (j4 >= j4lo && j4 < j4end) continue;
            float c = stat_c[r];
            float4 cv = make_float4(c, c, c, c);
            *(float4*)(att + ((size_t)(n * 8 + h) * 2048 + i0 + r) * 2048 + j4 * 4) = cv;
        }
    }
}

// ---------------------------------------------------------------------------
extern "C" void kernel_launch(void* const* d_in, const int* in_sizes, int n_in,
                              void* d_out, int out_size, void* d_ws, size_t ws_size,
                              hipStream_t stream) {
    const float* value = (const float*)d_in[0];
    const float* key_  = (const float*)d_in[1];
    const float* query = (const float*)d_in[2];
    const int*   mask  = (const int*)d_in[3];
    const float* Wv = (const float*)d_in[4];
    const float* bv = (const float*)d_in[5];
    const float* Wk = (const float*)d_in[6];
    const float* bk = (const float*)d_in[7];
    const float* Wq = (const float*)d_in[8];
    const float* bq = (const float*)d_in[9];
    const float* Wo = (const float*)d_in[10];
    const float* bo = (const float*)d_in[11];

    char* ws = (char*)d_ws;
    size_t off = 0;
    auto carve = [&](size_t bytes) -> char* {
        char* p = ws + off;
        off += (bytes + 255) & ~(size_t)255;
        return p;
    };
    const size_t XB = (size_t)8192 * 512 * 2;   // bf16 [8192,512]
    const size_t WB = (size_t)512 * 512 * 2;    // bf16 [512,512]
    u16* xqb = (u16*)carve(XB);
    u16* xkb = (u16*)carve(XB);
    u16* xvb = (u16*)carve(XB);
    u16* wqb = (u16*)carve(WB);
    u16* wkb = (u16*)carve(WB);
    u16* wvb = (u16*)carve(WB);
    u16* wob = (u16*)carve(WB);
    u16* qb  = (u16*)carve(XB);
    u16* kb  = (u16*)carve(XB);
    u16* vb2 = (u16*)carve(XB);
    u16* ohb = (u16*)carve(XB);
    float* sumv = (float*)carve(2048 * sizeof(float));

    CvtArgs ca;
    ca.src[0] = query; ca.dst[0] = xqb; ca.n[0] = 8192 * 512;
    ca.src[1] = key_;  ca.dst[1] = xkb; ca.n[1] = 8192 * 512;
    ca.src[2] = value; ca.dst[2] = xvb; ca.n[2] = 8192 * 512;
    ca.src[3] = Wq;    ca.dst[3] = wqb; ca.n[3] = 512 * 512;
    ca.src[4] = Wk;    ca.dst[4] = wkb; ca.n[4] = 512 * 512;
    ca.src[5] = Wv;    ca.dst[5] = wvb; ca.n[5] = 512 * 512;
    ca.src[6] = Wo;    ca.dst[6] = wob; ca.n[6] = 512 * 512;

    cvt_kernel<<<dim3(4096, 7), 256, 0, stream>>>(ca);
    gemm_qkv_kernel<<<dim3(64, 4, 3), 256, 0, stream>>>(
        xqb, xkb, xvb, wqb, wkb, wvb, bq, bk, bv, qb, kb, vb2);
    sumv_kernel<<<dim3(32), 256, 0, stream>>>(vb2, sumv);

    float* att = (float*)d_out + (size_t)4 * 2048 * 512;   // attention after out
    attn_kernel<<<dim3(2048), 256, 0, stream>>>(qb, kb, vb2, mask, sumv, att, ohb);
    gemm_out_kernel<<<dim3(64, 4, 1), 256, 0, stream>>>(ohb, wob, bo, (float*)d_out);
}

// Round 2
// 697.925 us; speedup vs baseline: 1.1626x; 1.1626x over previous
//
#include <hip/hip_runtime.h>

// ---------------------------------------------------------------------------
// WindowedSelfAttention: N=4, S=2048, E=512, H=8, D=64, WIN=256
// d_out: out [N,S,E] f32 (4.19M) then att [N,H,S,S] f32 (134M).
// Outside the +-128 window each attention row is one constant c = exp(-m)/den
// (reference zero-fills logits outside the band). Band via MFMA; rest via a
// dedicated streaming fill kernel.
// ---------------------------------------------------------------------------

typedef unsigned short u16;
typedef __bf16 bf16x8 __attribute__((ext_vector_type(8)));
typedef float  f32x4  __attribute__((ext_vector_type(4)));
typedef u16    u16x8  __attribute__((ext_vector_type(8)));

__device__ __forceinline__ u16 f2bf(float f) {
    union { float f; unsigned u; } x; x.f = f;
    unsigned u = x.u;
    u += 0x7fffu + ((u >> 16) & 1u);   // round-to-nearest-even
    return (u16)(u >> 16);
}
__device__ __forceinline__ float bf2f(u16 b) {
    union { unsigned u; float f; } x; x.u = ((unsigned)b) << 16;
    return x.f;
}
__device__ __forceinline__ int swzc(int c, int r) {
    return (c < 32) ? (c ^ (r & 7)) : c;
}

// ---------------------------------------------------------------------------
// f32 -> bf16 conversion, 7 tensors, exact block mapping (no idle blocks)
// t=0..2: 4096 blocks each; t=3..6: 256 blocks each. grid = 13312.
// ---------------------------------------------------------------------------
struct CvtArgs {
    const float* src[7];
    u16*         dst[7];
};

__global__ __launch_bounds__(256) void cvt_kernel(CvtArgs a) {
    int bid = blockIdx.x;
    int t, blk;
    if (bid < 12288) { t = bid >> 12; blk = bid & 4095; }
    else { int r = bid - 12288; t = 3 + (r >> 8); blk = r & 255; }
    int i = (blk * 256 + threadIdx.x) * 4;
    float4 v = *(const float4*)(a.src[t] + i);
    ushort4 o;
    o.x = f2bf(v.x); o.y = f2bf(v.y); o.z = f2bf(v.z); o.w = f2bf(v.w);
    *(ushort4*)(a.dst[t] + i) = o;
}

// ---------------------------------------------------------------------------
// m97-style bf16 GEMM: Y[M,512(each)] = X[M,512] @ W^T + b.
// 128x128 tile, BK=64, global_load_lds width 16 into LINEAR LDS with
// inverse-swizzled global source (chunk c = (lane&7)^(lane>>3)); reads apply
// the same XOR -> conflict-free ds_read_b128. 4 waves, each 64x64 (4x4 frags),
// 32 MFMA / K-step / wave.
// QKV=true: grid (64,12), bn>>2 selects tensor (different A and W rows, bf16
// out). QKV=false: grid (64,4), f32 out.
// ---------------------------------------------------------------------------
template <bool QKV>
__global__ __launch_bounds__(256) void gemm2(
    const u16* __restrict__ A0, const u16* __restrict__ A1, const u16* __restrict__ A2,
    const u16* __restrict__ B,
    const float* __restrict__ b0, const float* __restrict__ b1, const float* __restrict__ b2,
    u16* __restrict__ o0, u16* __restrict__ o1, u16* __restrict__ o2,
    float* __restrict__ fo)
{
    __shared__ __attribute__((aligned(16))) u16 As[128 * 64];
    __shared__ __attribute__((aligned(16))) u16 Bs[128 * 64];

    const int tid  = threadIdx.x;
    const int lane = tid & 63;
    const int w    = tid >> 6;
    const int bm   = blockIdx.x, bn = blockIdx.y;
    const int wm   = w >> 1, wn = w & 1;

    const int t = QKV ? (bn >> 2) : 0;
    const u16* A = (t == 0) ? A0 : (t == 1) ? A1 : A2;
    const u16* Ag = A + (size_t)bm * 128 * 512;
    const u16* Bg = B + (size_t)bn * 128 * 512;

    f32x4 acc[4][4];
#pragma unroll
    for (int m = 0; m < 4; ++m)
#pragma unroll
        for (int n = 0; n < 4; ++n) acc[m][n] = 0;

    const int swc = ((lane & 7) ^ (lane >> 3)) * 8;  // pre-swizzled source chunk

    for (int k0 = 0; k0 < 512; k0 += 64) {
#pragma unroll
        for (int i = 0; i < 4; ++i) {
            int row = (i * 4 + w) * 8 + (lane >> 3);
            const u16* ga = Ag + (size_t)row * 512 + k0 + swc;
            const u16* gb = Bg + (size_t)row * 512 + k0 + swc;
            __builtin_amdgcn_global_load_lds(
                (const __attribute__((address_space(1))) void*)ga,
                (__attribute__((address_space(3))) void*)(As + (i * 4 + w) * 512), 16, 0, 0);
            __builtin_amdgcn_global_load_lds(
                (const __attribute__((address_space(1))) void*)gb,
                (__attribute__((address_space(3))) void*)(Bs + (i * 4 + w) * 512), 16, 0, 0);
        }
        __syncthreads();   // drains vmcnt (global_load_lds) before reads

#pragma unroll
        for (int s = 0; s < 2; ++s) {
            bf16x8 af[4], bf[4];
            int c = s * 4 + (lane >> 4);
#pragma unroll
            for (int m = 0; m < 4; ++m) {
                int r = wm * 64 + m * 16 + (lane & 15);
                af[m] = *(const bf16x8*)(As + r * 64 + ((c ^ (r & 7)) * 8));
                int r2 = wn * 64 + m * 16 + (lane & 15);
                bf[m] = *(const bf16x8*)(Bs + r2 * 64 + ((c ^ (r2 & 7)) * 8));
            }
#pragma unroll
            for (int m = 0; m < 4; ++m)
#pragma unroll
                for (int n = 0; n < 4; ++n)
                    acc[m][n] = __builtin_amdgcn_mfma_f32_16x16x32_bf16(af[m], bf[n], acc[m][n], 0, 0, 0);
        }
        __syncthreads();
    }

    const float* bias = QKV ? ((t == 0) ? b0 : (t == 1) ? b1 : b2) : b0;
    u16* ob = QKV ? ((t == 0) ? o0 : (t == 1) ? o1 : o2) : o0;
    const int clbase = (bn & 3) * 128;

#pragma unroll
    for (int m = 0; m < 4; ++m) {
#pragma unroll
        for (int n = 0; n < 4; ++n) {
            int cl = clbase + wn * 64 + n * 16 + (lane & 15);
            float bb = bias[cl];
#pragma unroll
            for (int reg = 0; reg < 4; ++reg) {
                int row = bm * 128 + wm * 64 + m * 16 + (lane >> 4) * 4 + reg;
                float v = acc[m][n][reg] + bb;
                if (QKV) ob[(size_t)row * 512 + cl] = f2bf(v);
                else     fo[(size_t)row * 512 + cl] = v;
            }
        }
    }
}

// ---------------------------------------------------------------------------
// sumv[n,h,d] = sum_s v[n,s,h,d]; grid (32 nh, 8 sblk), vectorized, atomicAdd.
// sumv must be zeroed first (hipMemsetAsync).
// ---------------------------------------------------------------------------
__global__ __launch_bounds__(256) void sumv_kernel(const u16* __restrict__ vb,
                                                   float* __restrict__ sumv) {
    __shared__ float part[32][64];
    int nh = blockIdx.x, sb = blockIdx.y;
    int n = nh >> 3, h = nh & 7;
    int tid = threadIdx.x;
    int ch = tid & 7, sg = tid >> 3;
    size_t base = (size_t)n * 2048 * 512 + h * 64;
    float acc[8] = {0, 0, 0, 0, 0, 0, 0, 0};
    for (int p = 0; p < 8; ++p) {
        int s = sb * 256 + p * 32 + sg;
        u16x8 v = *(const u16x8*)(vb + base + (size_t)s * 512 + ch * 8);
#pragma unroll
        for (int r = 0; r < 8; ++r) acc[r] += bf2f(v[r]);
    }
#pragma unroll
    for (int r = 0; r < 8; ++r) part[sg][ch * 8 + r] = acc[r];
    __syncthreads();
    if (tid < 64) {
        float s = 0.f;
#pragma unroll
        for (int g = 0; g < 32; ++g) s += part[g][tid];
        atomicAdd(sumv + nh * 64 + tid, s);
    }
}

// ---------------------------------------------------------------------------
// Fused windowed attention band. One block = 32 query rows of one (n,h).
// Computes band scores via MFMA, softmax stats, writes band attention +
// A' = (att - c) in LDS, PV via MFMA, oh (bf16 head-out), c row constants to
// c_buf. The bulk constant fill is a separate streaming kernel.
// LDS: Qs/stats 4KB | Ks 36KB (aliased by A') | Vt [64][296] 37KB = 78.8KB.
// ---------------------------------------------------------------------------
__global__ __launch_bounds__(256) void attn_kernel(
    const u16* __restrict__ qb, const u16* __restrict__ kb,
    const u16* __restrict__ vb, const int* __restrict__ mask,
    const float* __restrict__ sumv, float* __restrict__ att,
    u16* __restrict__ oh, float* __restrict__ c_buf) {
    __shared__ __attribute__((aligned(16))) char lds[78848];
    u16*   Qs      = (u16*)lds;            // [32][64] bf16, chunk-swizzled
    float* stat_m  = (float*)lds;          // [32]  (aliases Qs after scores)
    float* stat_rd = (float*)(lds + 128);  // [32]
    float* stat_c  = (float*)(lds + 256);  // [32]
    float* red     = (float*)(lds + 384);  // [4][16]
    float* red2    = (float*)(lds + 640);  // [4][16]
    u16*   Ks      = (u16*)(lds + 4096);   // [288][64] bf16, chunk-swizzled
    u16*   Ab      = Ks;                   // [32][288] bf16 (after scores)
    u16*   Vt      = (u16*)(lds + 4096 + 36864); // [64][296] bf16 transposed

    const int tid  = threadIdx.x;
    const int lane = tid & 63;
    const int w    = tid >> 6;
    const int bid  = blockIdx.x;
    const int tile = bid & 63;
    const int h    = (bid >> 6) & 7;
    const int n    = bid >> 9;
    const int i0   = tile * 32;
    const int jlo  = max(0, i0 - 128);
    const float scale = 0.04419417382415922f;  // 1/sqrt(512)

    const size_t base_nh = (size_t)n * 2048 * 512 + h * 64;

    // ---- stage Qs [32][64] ----
    {
        int r = tid >> 3, ch = tid & 7;
        uint4 v = *(const uint4*)(qb + base_nh + (size_t)(i0 + r) * 512 + ch * 8);
        *(uint4*)((char*)Qs + r * 128 + ((ch ^ (r & 7)) << 4)) = v;
    }
    // ---- stage Ks [288][64] (zero-fill j >= 2048) ----
    for (int p = 0; p < 9; ++p) {
        int idx = p * 256 + tid;
        int jj = idx >> 3, ch = idx & 7;
        int j = jlo + jj;
        uint4 v = make_uint4(0, 0, 0, 0);
        if (j < 2048) v = *(const uint4*)(kb + base_nh + (size_t)j * 512 + ch * 8);
        *(uint4*)((char*)Ks + jj * 128 + ((ch ^ (jj & 7)) << 4)) = v;
    }
    // ---- stage Vt [64][296]: vector global reads, scalar LDS transpose ----
    for (int p = 0; p < 9; ++p) {
        int idx = p * 256 + tid;
        int jj = idx >> 3, ch = idx & 7;
        int j = jlo + jj;
        u16x8 tmp = {0, 0, 0, 0, 0, 0, 0, 0};
        if (j < 2048) tmp = *(const u16x8*)(vb + base_nh + (size_t)j * 512 + ch * 8);
#pragma unroll
        for (int r = 0; r < 8; ++r)
            Vt[(ch * 8 + r) * 296 + jj] = tmp[r];
    }
    __syncthreads();

    // ---- scores: S[32][288] = Q . K^T, wave -> 16 rows x 144 cols ----
    const int rbase = (w & 1) * 16;
    const int cbase = (w >> 1) * 144;
    f32x4 acc[9];
#pragma unroll
    for (int f = 0; f < 9; ++f) acc[f] = 0;

    bf16x8 aq[2];
    {
        int r = rbase + (lane & 15);
#pragma unroll
        for (int ks = 0; ks < 2; ++ks) {
            int kc = ks * 4 + (lane >> 4);
            aq[ks] = *(const bf16x8*)((char*)Qs + r * 128 + ((kc ^ (r & 7)) << 4));
        }
    }
#pragma unroll
    for (int f = 0; f < 9; ++f) {
        int jj = cbase + f * 16 + (lane & 15);
#pragma unroll
        for (int ks = 0; ks < 2; ++ks) {
            int kc = ks * 4 + (lane >> 4);
            bf16x8 bk_ = *(const bf16x8*)((char*)Ks + jj * 128 + ((kc ^ (jj & 7)) << 4));
            acc[f] = __builtin_amdgcn_mfma_f32_16x16x32_bf16(aq[ks], bk_, acc[f], 0, 0, 0);
        }
    }
    __syncthreads();   // Qs/Ks reads done; stats/A' may alias

    // ---- pass 1: logits + per-row max ----
    const int rowg = (lane >> 4) * 4;
    f32x4 lv[9];
    float mx[4] = {-__builtin_inff(), -__builtin_inff(), -__builtin_inff(), -__builtin_inff()};
#pragma unroll
    for (int f = 0; f < 9; ++f) {
        int jj = cbase + f * 16 + (lane & 15);
        int j = jlo + jj;
        int mk = (j < 2048) ? mask[n * 2048 + j] : 0;
#pragma unroll
        for (int reg = 0; reg < 4; ++reg) {
            int i = i0 + rbase + rowg + reg;
            bool inw = (j >= i - 128) && (j <= i + 128) && (j < 2048);
            float val = (inw && mk != 0) ? acc[f][reg] * scale : -__builtin_inff();
            lv[f][reg] = val;
            mx[reg] = fmaxf(mx[reg], val);
        }
    }
#pragma unroll
    for (int mskk = 1; mskk < 16; mskk <<= 1)
#pragma unroll
        for (int reg = 0; reg < 4; ++reg)
            mx[reg] = fmaxf(mx[reg], __shfl_xor(mx[reg], mskk, 64));
    if ((lane & 15) == 0) {
#pragma unroll
        for (int reg = 0; reg < 4; ++reg) red[w * 16 + rowg + reg] = mx[reg];
    }
    __syncthreads();
    if (tid < 32) {
        int r = tid;
        int wa = (r < 16) ? 0 : 1, rr = r & 15;
        stat_m[r] = fmaxf(fmaxf(red[wa * 16 + rr], red[(wa + 2) * 16 + rr]), 0.0f);
    }
    __syncthreads();

    // ---- pass 2: denom ----
    float m4[4];
#pragma unroll
    for (int reg = 0; reg < 4; ++reg) m4[reg] = stat_m[rbase + rowg + reg];
    float sm[4] = {0, 0, 0, 0};
#pragma unroll
    for (int f = 0; f < 9; ++f)
#pragma unroll
        for (int reg = 0; reg < 4; ++reg)
            sm[reg] += __expf(lv[f][reg] - m4[reg]);
#pragma unroll
    for (int mskk = 1; mskk < 16; mskk <<= 1)
#pragma unroll
        for (int reg = 0; reg < 4; ++reg)
            sm[reg] += __shfl_xor(sm[reg], mskk, 64);
    if ((lane & 15) == 0) {
#pragma unroll
        for (int reg = 0; reg < 4; ++reg) red2[w * 16 + rowg + reg] = sm[reg];
    }
    __syncthreads();
    if (tid < 32) {
        int r = tid, gi = i0 + r;
        int wa = (r < 16) ? 0 : 1, rr = r & 15;
        float s = red2[wa * 16 + rr] + red2[(wa + 2) * 16 + rr];
        int lo = max(0, gi - 128), hi = min(2048, gi + 129);
        float em = __expf(-stat_m[r]);
        float denom = s + (float)(2048 - (hi - lo)) * em;
        float rd = 1.0f / denom;
        stat_rd[r] = rd;
        float c = em * rd;
        stat_c[r] = c;
        c_buf[(size_t)(n * 8 + h) * 2048 + gi] = c;
    }
    __syncthreads();

    // ---- pass 3: band attention writes + A' = (att - c) bf16 in LDS ----
    float rd4[4], c4[4];
#pragma unroll
    for (int reg = 0; reg < 4; ++reg) {
        rd4[reg] = stat_rd[rbase + rowg + reg];
        c4[reg] = stat_c[rbase + rowg + reg];
    }
#pragma unroll
    for (int f = 0; f < 9; ++f) {
        int jj = cbase + f * 16 + (lane & 15);
        int j = jlo + jj;
        int jc = jj >> 3;
#pragma unroll
        for (int reg = 0; reg < 4; ++reg) {
            int it = rbase + rowg + reg;
            int i = i0 + it;
            bool inw = (j >= i - 128) && (j <= i + 128) && (j < 2048);
            float e = __expf(lv[f][reg] - m4[reg]);
            float a = inw ? e * rd4[reg] : c4[reg];
            if (j < 2048)
                att[((size_t)(n * 8 + h) * 2048 + i) * 2048 + j] = a;
            float ab = inw ? (a - c4[reg]) : 0.0f;
            ((u16*)((char*)Ab + it * 576 + (swzc(jc, it) << 4)))[jj & 7] = f2bf(ab);
        }
    }
    __syncthreads();

    // ---- PV: out[32][64] = A'[32][288] @ V[288][64] (via Vt), + c*sumv ----
    const int rb2 = (w & 1) * 16;
    const int db  = (w >> 1) * 32;
    f32x4 po[2];
    po[0] = 0; po[1] = 0;
#pragma unroll
    for (int ks = 0; ks < 9; ++ks) {
        int kc = ks * 4 + (lane >> 4);
        int it = rb2 + (lane & 15);
        bf16x8 af = *(const bf16x8*)((char*)Ab + it * 576 + (swzc(kc, it) << 4));
#pragma unroll
        for (int f = 0; f < 2; ++f) {
            int d = db + f * 16 + (lane & 15);
            bf16x8 bv_ = *(const bf16x8*)(Vt + d * 296 + kc * 8);
            po[f] = __builtin_amdgcn_mfma_f32_16x16x32_bf16(af, bv_, po[f], 0, 0, 0);
        }
    }
    {
        const float* svp = sumv + (size_t)(n * 8 + h) * 64;
#pragma unroll
        for (int f = 0; f < 2; ++f) {
            int d = db + f * 16 + (lane & 15);
            float sv = svp[d];
#pragma unroll
            for (int reg = 0; reg < 4; ++reg) {
                int it = rb2 + rowg + reg;
                float val = po[f][reg] + stat_c[it] * sv;
                oh[base_nh + (size_t)(i0 + it) * 512 + d] = f2bf(val);
            }
        }
    }
}

// ---------------------------------------------------------------------------
// Streaming constant fill: everything outside each tile's union band gets the
// per-row constant c. Pure float4 stores; ~460 MB at HBM write BW.
// ---------------------------------------------------------------------------
__global__ __launch_bounds__(256) void fill_kernel(const float* __restrict__ c_buf,
                                                   float* __restrict__ att) {
    __shared__ float cs[32];
    int bid = blockIdx.x;
    int tile = bid & 63, h = (bid >> 6) & 7, n = bid >> 9;
    int i0 = tile * 32;
    int jlo = max(0, i0 - 128);
    int jend = min(2048, jlo + 288);
    int j4lo = jlo >> 2, j4end = jend >> 2;
    int tid = threadIdx.x;
    if (tid < 32) cs[tid] = c_buf[(size_t)(n * 8 + h) * 2048 + i0 + tid];
    __syncthreads();
    size_t rowbase = ((size_t)(n * 8 + h) * 2048 + i0) * 2048;
    for (int idx = tid; idx < 32 * 512; idx += 256) {
        int r = idx >> 9, j4 = idx & 511;
        if (j4 >= j4lo && j4 < j4end) continue;
        float c = cs[r];
        *(float4*)(att + rowbase + (size_t)r * 2048 + j4 * 4) = make_float4(c, c, c, c);
    }
}

// ---------------------------------------------------------------------------
extern "C" void kernel_launch(void* const* d_in, const int* in_sizes, int n_in,
                              void* d_out, int out_size, void* d_ws, size_t ws_size,
                              hipStream_t stream) {
    const float* value = (const float*)d_in[0];
    const float* key_  = (const float*)d_in[1];
    const float* query = (const float*)d_in[2];
    const int*   mask  = (const int*)d_in[3];
    const float* Wv = (const float*)d_in[4];
    const float* bv = (const float*)d_in[5];
    const float* Wk = (const float*)d_in[6];
    const float* bk = (const float*)d_in[7];
    const float* Wq = (const float*)d_in[8];
    const float* bq = (const float*)d_in[9];
    const float* Wo = (const float*)d_in[10];
    const float* bo = (const float*)d_in[11];

    char* ws = (char*)d_ws;
    size_t off = 0;
    auto carve = [&](size_t bytes) -> char* {
        char* p = ws + off;
        off += (bytes + 255) & ~(size_t)255;
        return p;
    };
    const size_t XB = (size_t)8192 * 512 * 2;   // bf16 [8192,512]
    const size_t WB = (size_t)512 * 512 * 2;    // bf16 [512,512]
    u16* xqb  = (u16*)carve(XB);
    u16* xkb  = (u16*)carve(XB);
    u16* xvb  = (u16*)carve(XB);
    u16* wqkv = (u16*)carve(3 * WB);            // [1536,512]: Wq rows, Wk, Wv
    u16* wob  = (u16*)carve(WB);
    u16* qb   = (u16*)carve(XB);
    u16* kb   = (u16*)carve(XB);
    u16* vb2  = (u16*)carve(XB);
    u16* ohb  = (u16*)carve(XB);
    float* sumv  = (float*)carve(2048 * sizeof(float));
    float* c_buf = (float*)carve((size_t)65536 * sizeof(float));

    hipMemsetAsync(sumv, 0, 2048 * sizeof(float), stream);

    CvtArgs ca;
    ca.src[0] = query; ca.dst[0] = xqb;
    ca.src[1] = key_;  ca.dst[1] = xkb;
    ca.src[2] = value; ca.dst[2] = xvb;
    ca.src[3] = Wq;    ca.dst[3] = wqkv;
    ca.src[4] = Wk;    ca.dst[4] = wqkv + (size_t)512 * 512;
    ca.src[5] = Wv;    ca.dst[5] = wqkv + (size_t)1024 * 512;
    ca.src[6] = Wo;    ca.dst[6] = wob;

    cvt_kernel<<<dim3(13312), 256, 0, stream>>>(ca);
    gemm2<true><<<dim3(64, 12), 256, 0, stream>>>(
        xqb, xkb, xvb, wqkv, bq, bk, bv, qb, kb, vb2, nullptr);
    sumv_kernel<<<dim3(32, 8), 256, 0, stream>>>(vb2, sumv);

    float* att = (float*)d_out + (size_t)4 * 2048 * 512;
    attn_kernel<<<dim3(2048), 256, 0, stream>>>(qb, kb, vb2, mask, sumv, att, ohb, c_buf);
    gemm2<false><<<dim3(64, 4), 256, 0, stream>>>(
        ohb, nullptr, nullptr, wob, bo, nullptr, nullptr, nullptr, nullptr, nullptr, (float*)d_out);
    fill_kernel<<<dim3(2048), 256, 0, stream>>>(c_buf, att);
}

// Round 3
// 670.879 us; speedup vs baseline: 1.2095x; 1.0403x over previous
//
#include <hip/hip_runtime.h>

// ---------------------------------------------------------------------------
// WindowedSelfAttention: N=4, S=2048, E=512, H=8, D=64, WIN=256
// d_out: out [N,S,E] f32 (4.19M) then att [N,H,S,S] f32 (134M).
// Outside the +-128 window each attention row is one constant c = exp(-m)/den
// (reference zero-fills logits outside the band). Band via MFMA; rest via a
// dedicated streaming fill kernel.
// ---------------------------------------------------------------------------

typedef unsigned short u16;
typedef __bf16 bf16x8 __attribute__((ext_vector_type(8)));
typedef float  f32x4  __attribute__((ext_vector_type(4)));
typedef u16    u16x8  __attribute__((ext_vector_type(8)));

#define GLOAD_LDS(gsrc, ldst)                                                  \
    __builtin_amdgcn_global_load_lds(                                          \
        (const __attribute__((address_space(1))) void*)(gsrc),                 \
        (__attribute__((address_space(3))) void*)(ldst), 16, 0, 0)

__device__ __forceinline__ u16 f2bf(float f) {
    union { float f; unsigned u; } x; x.f = f;
    unsigned u = x.u;
    u += 0x7fffu + ((u >> 16) & 1u);   // round-to-nearest-even
    return (u16)(u >> 16);
}
__device__ __forceinline__ int swzc(int c, int r) {
    return (c < 32) ? (c ^ (r & 7)) : c;
}

// ---------------------------------------------------------------------------
// f32 -> bf16 conversion, 7 tensors, exact block mapping (no idle blocks)
// t=0..2: 4096 blocks each; t=3..6: 256 blocks each. grid = 13312.
// ---------------------------------------------------------------------------
struct CvtArgs {
    const float* src[7];
    u16*         dst[7];
};

__global__ __launch_bounds__(256) void cvt_kernel(CvtArgs a) {
    int bid = blockIdx.x;
    int t, blk;
    if (bid < 12288) { t = bid >> 12; blk = bid & 4095; }
    else { int r = bid - 12288; t = 3 + (r >> 8); blk = r & 255; }
    int i = (blk * 256 + threadIdx.x) * 4;
    float4 v = *(const float4*)(a.src[t] + i);
    ushort4 o;
    o.x = f2bf(v.x); o.y = f2bf(v.y); o.z = f2bf(v.z); o.w = f2bf(v.w);
    *(ushort4*)(a.dst[t] + i) = o;
}

// ---------------------------------------------------------------------------
// QKV GEMM (m97-style): Y[M,512] = X[M,512] @ W^T + b for q,k,v stacked.
// 128x128 tile, BK=64, global_load_lds w16, linear LDS + source-side XOR
// swizzle, conflict-free ds_read_b128. grid (64,12); bn>>2 selects tensor.
// V blocks (t==2) also accumulate column sums into sumv (atomicAdd).
// ---------------------------------------------------------------------------
__global__ __launch_bounds__(256) void gemm_qkv(
    const u16* __restrict__ A0, const u16* __restrict__ A1, const u16* __restrict__ A2,
    const u16* __restrict__ B,
    const float* __restrict__ b0, const float* __restrict__ b1, const float* __restrict__ b2,
    u16* __restrict__ o0, u16* __restrict__ o1, u16* __restrict__ o2,
    float* __restrict__ sumv)
{
    __shared__ __attribute__((aligned(16))) u16 As[128 * 64];
    __shared__ __attribute__((aligned(16))) u16 Bs[128 * 64];

    const int tid  = threadIdx.x;
    const int lane = tid & 63;
    const int w    = tid >> 6;
    const int bm   = blockIdx.x, bn = blockIdx.y;
    const int wm   = w >> 1, wn = w & 1;

    const int t = bn >> 2;
    const u16* A = (t == 0) ? A0 : (t == 1) ? A1 : A2;
    const u16* Ag = A + (size_t)bm * 128 * 512;
    const u16* Bg = B + (size_t)bn * 128 * 512;

    f32x4 acc[4][4];
#pragma unroll
    for (int m = 0; m < 4; ++m)
#pragma unroll
        for (int n = 0; n < 4; ++n) acc[m][n] = 0;

    const int swc = ((lane & 7) ^ (lane >> 3)) * 8;  // pre-swizzled source chunk

    for (int k0 = 0; k0 < 512; k0 += 64) {
#pragma unroll
        for (int i = 0; i < 4; ++i) {
            int g = i * 4 + w;
            int row = g * 8 + (lane >> 3);
            GLOAD_LDS(Ag + (size_t)row * 512 + k0 + swc, As + g * 512);
            GLOAD_LDS(Bg + (size_t)row * 512 + k0 + swc, Bs + g * 512);
        }
        __syncthreads();   // drains vmcnt before reads

#pragma unroll
        for (int s = 0; s < 2; ++s) {
            bf16x8 af[4], bf[4];
            int c = s * 4 + (lane >> 4);
#pragma unroll
            for (int m = 0; m < 4; ++m) {
                int r = wm * 64 + m * 16 + (lane & 15);
                af[m] = *(const bf16x8*)(As + r * 64 + ((c ^ (r & 7)) * 8));
                int r2 = wn * 64 + m * 16 + (lane & 15);
                bf[m] = *(const bf16x8*)(Bs + r2 * 64 + ((c ^ (r2 & 7)) * 8));
            }
#pragma unroll
            for (int m = 0; m < 4; ++m)
#pragma unroll
                for (int n = 0; n < 4; ++n)
                    acc[m][n] = __builtin_amdgcn_mfma_f32_16x16x32_bf16(af[m], bf[n], acc[m][n], 0, 0, 0);
        }
        __syncthreads();
    }

    const float* bias = (t == 0) ? b0 : (t == 1) ? b1 : b2;
    u16* ob = (t == 0) ? o0 : (t == 1) ? o1 : o2;
    const int clbase = (bn & 3) * 128;

#pragma unroll
    for (int m = 0; m < 4; ++m) {
#pragma unroll
        for (int n = 0; n < 4; ++n) {
            int cl = clbase + wn * 64 + n * 16 + (lane & 15);
            float bb = bias[cl];
#pragma unroll
            for (int reg = 0; reg < 4; ++reg) {
                int row = bm * 128 + wm * 64 + m * 16 + (lane >> 4) * 4 + reg;
                ob[(size_t)row * 512 + cl] = f2bf(acc[m][n][reg] + bb);
            }
        }
    }

    // V-tensor blocks: column sums (over this block's 128 rows) -> sumv[n][col]
    if (t == 2) {
        int nb = bm >> 4;                       // batch index (128 | 2048)
#pragma unroll
        for (int n = 0; n < 4; ++n) {
            float s = 0.f;
#pragma unroll
            for (int m = 0; m < 4; ++m)
#pragma unroll
                for (int reg = 0; reg < 4; ++reg) s += acc[m][n][reg];
            s += __shfl_xor(s, 16, 64);
            s += __shfl_xor(s, 32, 64);
            if (lane < 16) {
                int cl = clbase + wn * 64 + n * 16 + lane;
                atomicAdd(sumv + nb * 512 + cl, s);
            }
        }
    }
}

// ---------------------------------------------------------------------------
// Out projection: fo[8192,512] = A[8192,512] @ Wo^T + bo.  128x64 tile,
// grid (64,8) = 512 blocks (2/CU). 4 waves, wave tile 64x32 (4x2 frags).
// ---------------------------------------------------------------------------
__global__ __launch_bounds__(256) void gemm_o(
    const u16* __restrict__ A, const u16* __restrict__ B,
    const float* __restrict__ bias, float* __restrict__ fo)
{
    __shared__ __attribute__((aligned(16))) u16 As[128 * 64];
    __shared__ __attribute__((aligned(16))) u16 Bs[64 * 64];

    const int tid  = threadIdx.x;
    const int lane = tid & 63;
    const int w    = tid >> 6;
    const int bm   = blockIdx.x, bn = blockIdx.y;
    const int wm   = w >> 1, wn = w & 1;

    const u16* Ag = A + (size_t)bm * 128 * 512;
    const u16* Bg = B + (size_t)bn * 64 * 512;

    f32x4 acc[4][2];
#pragma unroll
    for (int m = 0; m < 4; ++m) { acc[m][0] = 0; acc[m][1] = 0; }

    const int swc = ((lane & 7) ^ (lane >> 3)) * 8;

    for (int k0 = 0; k0 < 512; k0 += 64) {
#pragma unroll
        for (int i = 0; i < 4; ++i) {
            int g = i * 4 + w;
            GLOAD_LDS(Ag + (size_t)(g * 8 + (lane >> 3)) * 512 + k0 + swc, As + g * 512);
        }
#pragma unroll
        for (int i = 0; i < 2; ++i) {
            int g = i * 4 + w;
            GLOAD_LDS(Bg + (size_t)(g * 8 + (lane >> 3)) * 512 + k0 + swc, Bs + g * 512);
        }
        __syncthreads();

#pragma unroll
        for (int s = 0; s < 2; ++s) {
            bf16x8 af[4], bf[2];
            int c = s * 4 + (lane >> 4);
#pragma unroll
            for (int m = 0; m < 4; ++m) {
                int r = wm * 64 + m * 16 + (lane & 15);
                af[m] = *(const bf16x8*)(As + r * 64 + ((c ^ (r & 7)) * 8));
            }
#pragma unroll
            for (int n = 0; n < 2; ++n) {
                int r2 = wn * 32 + n * 16 + (lane & 15);
                bf[n] = *(const bf16x8*)(Bs + r2 * 64 + ((c ^ (r2 & 7)) * 8));
            }
#pragma unroll
            for (int m = 0; m < 4; ++m)
#pragma unroll
                for (int n = 0; n < 2; ++n)
                    acc[m][n] = __builtin_amdgcn_mfma_f32_16x16x32_bf16(af[m], bf[n], acc[m][n], 0, 0, 0);
        }
        __syncthreads();
    }

#pragma unroll
    for (int m = 0; m < 4; ++m) {
#pragma unroll
        for (int n = 0; n < 2; ++n) {
            int cl = bn * 64 + wn * 32 + n * 16 + (lane & 15);
            float bb = bias[cl];
#pragma unroll
            for (int reg = 0; reg < 4; ++reg) {
                int row = bm * 128 + wm * 64 + m * 16 + (lane >> 4) * 4 + reg;
                fo[(size_t)row * 512 + cl] = acc[m][n][reg] + bb;
            }
        }
    }
}

// ---------------------------------------------------------------------------
// Fused windowed attention band. One block = 32 query rows of one (n,h).
// K/Q staged via global_load_lds (linear LDS, source-side XOR swizzle; OOB
// rows clamped -- masked later so garbage is harmless). V transposed in LDS
// with chunk-XOR pjc = jc ^ (d>>3) -> 2-way (free) write banks.
// XCD-chunked block swizzle keeps one (n,h)'s 64 tiles on one XCD L2.
// LDS: Qs/stats 4KB | Ks 36KB (aliased by A') | Vt [64][296] 37KB = 78.8KB.
// ---------------------------------------------------------------------------
__global__ __launch_bounds__(256) void attn_kernel(
    const u16* __restrict__ qb, const u16* __restrict__ kb,
    const u16* __restrict__ vb, const int* __restrict__ mask,
    const float* __restrict__ sumv, float* __restrict__ att,
    u16* __restrict__ oh, float* __restrict__ c_buf) {
    __shared__ __attribute__((aligned(16))) char lds[78848];
    u16*   Qs      = (u16*)lds;            // [32][64] bf16, chunk-swizzled
    float* stat_m  = (float*)lds;          // [32]  (aliases Qs after scores)
    float* stat_rd = (float*)(lds + 128);  // [32]
    float* stat_c  = (float*)(lds + 256);  // [32]
    float* red     = (float*)(lds + 384);  // [4][16]
    float* red2    = (float*)(lds + 640);  // [4][16]
    u16*   Ks      = (u16*)(lds + 4096);   // [288][64] bf16, chunk-swizzled
    u16*   Ab      = Ks;                   // [32][288] bf16 (after scores)
    u16*   Vt      = (u16*)(lds + 4096 + 36864); // [64][296] bf16 transposed

    const int tid  = threadIdx.x;
    const int lane = tid & 63;
    const int w    = tid >> 6;
    const int bid0 = blockIdx.x;
    const int bid  = (bid0 & 7) * 256 + (bid0 >> 3);   // XCD-chunked swizzle
    const int tile = bid & 63;
    const int h    = (bid >> 6) & 7;
    const int n    = bid >> 9;
    const int i0   = tile * 32;
    const int jlo  = max(0, i0 - 128);
    const float scale = 0.04419417382415922f;  // 1/sqrt(512)

    const size_t base_nh = (size_t)n * 2048 * 512 + h * 64;
    const int lr = lane >> 3;              // row-in-group for staging
    const int swg = ((lane & 7) ^ lr) * 8; // source chunk (XOR swizzle)

    // ---- stage Qs [32][64] via global_load_lds (1 instr/wave) ----
    GLOAD_LDS(qb + base_nh + (size_t)(i0 + w * 8 + lr) * 512 + swg, Qs + w * 512);
    // ---- stage Ks [288][64] (rows >= 2048 clamped; masked later) ----
    for (int p = 0; p < 9; ++p) {
        int g = p * 4 + w;                 // row group 0..35
        int j = min(jlo + g * 8 + lr, 2047);
        GLOAD_LDS(kb + base_nh + (size_t)j * 512 + swg, Ks + g * 512);
    }
    // ---- stage Vt [64][296] = V^T; chunk-XOR write swizzle (2-way banks) ----
    for (int p = 0; p < 9; ++p) {
        int idx = p * 256 + tid;
        int jj = idx >> 3, ch = idx & 7;
        int j = jlo + jj;
        u16x8 tmp = {0, 0, 0, 0, 0, 0, 0, 0};
        if (j < 2048) tmp = *(const u16x8*)(vb + base_nh + (size_t)j * 512 + ch * 8);
        int jc = jj >> 3, jr = jj & 7;
        int pjc = (jc < 32) ? (jc ^ ch) : jc;
#pragma unroll
        for (int r = 0; r < 8; ++r)
            Vt[(ch * 8 + r) * 296 + pjc * 8 + jr] = tmp[r];
    }
    __syncthreads();

    // ---- scores: S[32][288] = Q . K^T, wave -> 16 rows x 144 cols ----
    const int rbase = (w & 1) * 16;
    const int cbase = (w >> 1) * 144;
    f32x4 acc[9];
#pragma unroll
    for (int f = 0; f < 9; ++f) acc[f] = 0;

    bf16x8 aq[2];
    {
        int r = rbase + (lane & 15);
#pragma unroll
        for (int ks = 0; ks < 2; ++ks) {
            int kc = ks * 4 + (lane >> 4);
            aq[ks] = *(const bf16x8*)(Qs + r * 64 + ((kc ^ (r & 7)) * 8));
        }
    }
#pragma unroll
    for (int f = 0; f < 9; ++f) {
        int jj = cbase + f * 16 + (lane & 15);
#pragma unroll
        for (int ks = 0; ks < 2; ++ks) {
            int kc = ks * 4 + (lane >> 4);
            bf16x8 bk_ = *(const bf16x8*)(Ks + jj * 64 + ((kc ^ (jj & 7)) * 8));
            acc[f] = __builtin_amdgcn_mfma_f32_16x16x32_bf16(aq[ks], bk_, acc[f], 0, 0, 0);
        }
    }
    __syncthreads();   // Qs/Ks reads done; stats/A' may alias

    // ---- pass 1: logits + per-row max ----
    const int rowg = (lane >> 4) * 4;
    f32x4 lv[9];
    float mx[4] = {-__builtin_inff(), -__builtin_inff(), -__builtin_inff(), -__builtin_inff()};
#pragma unroll
    for (int f = 0; f < 9; ++f) {
        int jj = cbase + f * 16 + (lane & 15);
        int j = jlo + jj;
        int mk = (j < 2048) ? mask[n * 2048 + j] : 0;
#pragma unroll
        for (int reg = 0; reg < 4; ++reg) {
            int i = i0 + rbase + rowg + reg;
            bool inw = (j >= i - 128) && (j <= i + 128) && (j < 2048);
            float val = (inw && mk != 0) ? acc[f][reg] * scale : -__builtin_inff();
            lv[f][reg] = val;
            mx[reg] = fmaxf(mx[reg], val);
        }
    }
#pragma unroll
    for (int mskk = 1; mskk < 16; mskk <<= 1)
#pragma unroll
        for (int reg = 0; reg < 4; ++reg)
            mx[reg] = fmaxf(mx[reg], __shfl_xor(mx[reg], mskk, 64));
    if ((lane & 15) == 0) {
#pragma unroll
        for (int reg = 0; reg < 4; ++reg) red[w * 16 + rowg + reg] = mx[reg];
    }
    __syncthreads();
    if (tid < 32) {
        int r = tid;
        int wa = (r < 16) ? 0 : 1, rr = r & 15;
        stat_m[r] = fmaxf(fmaxf(red[wa * 16 + rr], red[(wa + 2) * 16 + rr]), 0.0f);
    }
    __syncthreads();

    // ---- pass 2: denom ----
    float m4[4];
#pragma unroll
    for (int reg = 0; reg < 4; ++reg) m4[reg] = stat_m[rbase + rowg + reg];
    float sm[4] = {0, 0, 0, 0};
#pragma unroll
    for (int f = 0; f < 9; ++f)
#pragma unroll
        for (int reg = 0; reg < 4; ++reg)
            sm[reg] += __expf(lv[f][reg] - m4[reg]);
#pragma unroll
    for (int mskk = 1; mskk < 16; mskk <<= 1)
#pragma unroll
        for (int reg = 0; reg < 4; ++reg)
            sm[reg] += __shfl_xor(sm[reg], mskk, 64);
    if ((lane & 15) == 0) {
#pragma unroll
        for (int reg = 0; reg < 4; ++reg) red2[w * 16 + rowg + reg] = sm[reg];
    }
    __syncthreads();
    if (tid < 32) {
        int r = tid, gi = i0 + r;
        int wa = (r < 16) ? 0 : 1, rr = r & 15;
        float s = red2[wa * 16 + rr] + red2[(wa + 2) * 16 + rr];
        int lo = max(0, gi - 128), hi = min(2048, gi + 129);
        float em = __expf(-stat_m[r]);
        float denom = s + (float)(2048 - (hi - lo)) * em;
        float rd = 1.0f / denom;
        stat_rd[r] = rd;
        float c = em * rd;
        stat_c[r] = c;
        c_buf[(size_t)(n * 8 + h) * 2048 + gi] = c;
    }
    __syncthreads();

    // ---- pass 3: band attention writes + A' = (att - c) bf16 in LDS ----
    float rd4[4], c4[4];
#pragma unroll
    for (int reg = 0; reg < 4; ++reg) {
        rd4[reg] = stat_rd[rbase + rowg + reg];
        c4[reg] = stat_c[rbase + rowg + reg];
    }
#pragma unroll
    for (int f = 0; f < 9; ++f) {
        int jj = cbase + f * 16 + (lane & 15);
        int j = jlo + jj;
        int jc = jj >> 3;
#pragma unroll
        for (int reg = 0; reg < 4; ++reg) {
            int it = rbase + rowg + reg;
            int i = i0 + it;
            bool inw = (j >= i - 128) && (j <= i + 128) && (j < 2048);
            float e = __expf(lv[f][reg] - m4[reg]);
            float a = inw ? e * rd4[reg] : c4[reg];
            if (j < 2048)
                att[((size_t)(n * 8 + h) * 2048 + i) * 2048 + j] = a;
            float ab = inw ? (a - c4[reg]) : 0.0f;
            ((u16*)((char*)Ab + it * 576 + (swzc(jc, it) << 4)))[jj & 7] = f2bf(ab);
        }
    }
    __syncthreads();

    // ---- PV: out[32][64] = A'[32][288] @ V[288][64] (via Vt), + c*sumv ----
    const int rb2 = (w & 1) * 16;
    const int db  = (w >> 1) * 32;
    f32x4 po[2];
    po[0] = 0; po[1] = 0;
#pragma unroll
    for (int ks = 0; ks < 9; ++ks) {
        int kc = ks * 4 + (lane >> 4);
        int it = rb2 + (lane & 15);
        bf16x8 af = *(const bf16x8*)((char*)Ab + it * 576 + (swzc(kc, it) << 4));
#pragma unroll
        for (int f = 0; f < 2; ++f) {
            int d = db + f * 16 + (lane & 15);
            int phys = (kc < 32) ? (kc ^ (d >> 3)) : kc;
            bf16x8 bv_ = *(const bf16x8*)(Vt + d * 296 + phys * 8);
            po[f] = __builtin_amdgcn_mfma_f32_16x16x32_bf16(af, bv_, po[f], 0, 0, 0);
        }
    }
    {
        const float* svp = sumv + (size_t)n * 512 + h * 64;
#pragma unroll
        for (int f = 0; f < 2; ++f) {
            int d = db + f * 16 + (lane & 15);
            float sv = svp[d];
#pragma unroll
            for (int reg = 0; reg < 4; ++reg) {
                int it = rb2 + rowg + reg;
                float val = po[f][reg] + stat_c[it] * sv;
                oh[base_nh + (size_t)(i0 + it) * 512 + d] = f2bf(val);
            }
        }
    }
}

// ---------------------------------------------------------------------------
// Streaming constant fill: everything outside each tile's union band gets the
// per-row constant c. Pure float4 stores.
// ---------------------------------------------------------------------------
__global__ __launch_bounds__(256) void fill_kernel(const float* __restrict__ c_buf,
                                                   float* __restrict__ att) {
    __shared__ float cs[32];
    int bid = blockIdx.x;
    int tile = bid & 63, h = (bid >> 6) & 7, n = bid >> 9;
    int i0 = tile * 32;
    int jlo = max(0, i0 - 128);
    int jend = min(2048, jlo + 288);
    int j4lo = jlo >> 2, j4end = jend >> 2;
    int tid = threadIdx.x;
    if (tid < 32) cs[tid] = c_buf[(size_t)(n * 8 + h) * 2048 + i0 + tid];
    __syncthreads();
    size_t rowbase = ((size_t)(n * 8 + h) * 2048 + i0) * 2048;
    for (int idx = tid; idx < 32 * 512; idx += 256) {
        int r = idx >> 9, j4 = idx & 511;
        if (j4 >= j4lo && j4 < j4end) continue;
        float c = cs[r];
        *(float4*)(att + rowbase + (size_t)r * 2048 + j4 * 4) = make_float4(c, c, c, c);
    }
}

// ---------------------------------------------------------------------------
extern "C" void kernel_launch(void* const* d_in, const int* in_sizes, int n_in,
                              void* d_out, int out_size, void* d_ws, size_t ws_size,
                              hipStream_t stream) {
    const float* value = (const float*)d_in[0];
    const float* key_  = (const float*)d_in[1];
    const float* query = (const float*)d_in[2];
    const int*   mask  = (const int*)d_in[3];
    const float* Wv = (const float*)d_in[4];
    const float* bv = (const float*)d_in[5];
    const float* Wk = (const float*)d_in[6];
    const float* bk = (const float*)d_in[7];
    const float* Wq = (const float*)d_in[8];
    const float* bq = (const float*)d_in[9];
    const float* Wo = (const float*)d_in[10];
    const float* bo = (const float*)d_in[11];

    char* ws = (char*)d_ws;
    size_t off = 0;
    auto carve = [&](size_t bytes) -> char* {
        char* p = ws + off;
        off += (bytes + 255) & ~(size_t)255;
        return p;
    };
    const size_t XB = (size_t)8192 * 512 * 2;   // bf16 [8192,512]
    const size_t WB = (size_t)512 * 512 * 2;    // bf16 [512,512]
    u16* xqb  = (u16*)carve(XB);
    u16* xkb  = (u16*)carve(XB);
    u16* xvb  = (u16*)carve(XB);
    u16* wqkv = (u16*)carve(3 * WB);            // [1536,512]: Wq rows, Wk, Wv
    u16* wob  = (u16*)carve(WB);
    u16* qb   = (u16*)carve(XB);
    u16* kb   = (u16*)carve(XB);
    u16* vb2  = (u16*)carve(XB);
    u16* ohb  = (u16*)carve(XB);
    float* sumv  = (float*)carve(2048 * sizeof(float));
    float* c_buf = (float*)carve((size_t)65536 * sizeof(float));

    hipMemsetAsync(sumv, 0, 2048 * sizeof(float), stream);

    CvtArgs ca;
    ca.src[0] = query; ca.dst[0] = xqb;
    ca.src[1] = key_;  ca.dst[1] = xkb;
    ca.src[2] = value; ca.dst[2] = xvb;
    ca.src[3] = Wq;    ca.dst[3] = wqkv;
    ca.src[4] = Wk;    ca.dst[4] = wqkv + (size_t)512 * 512;
    ca.src[5] = Wv;    ca.dst[5] = wqkv + (size_t)1024 * 512;
    ca.src[6] = Wo;    ca.dst[6] = wob;

    cvt_kernel<<<dim3(13312), 256, 0, stream>>>(ca);
    gemm_qkv<<<dim3(64, 12), 256, 0, stream>>>(
        xqb, xkb, xvb, wqkv, bq, bk, bv, qb, kb, vb2, sumv);

    float* att = (float*)d_out + (size_t)4 * 2048 * 512;
    attn_kernel<<<dim3(2048), 256, 0, stream>>>(qb, kb, vb2, mask, sumv, att, ohb, c_buf);
    gemm_o<<<dim3(64, 8), 256, 0, stream>>>(ohb, wob, bo, (float*)d_out);
    fill_kernel<<<dim3(2048), 256, 0, stream>>>(c_buf, att);
}

// Round 5
// 663.435 us; speedup vs baseline: 1.2230x; 1.0112x over previous
//
#include <hip/hip_runtime.h>

// ---------------------------------------------------------------------------
// WindowedSelfAttention: N=4, S=2048, E=512, H=8, D=64, WIN=256
// d_out: out [N,S,E] f32 (4.19M) then att [N,H,S,S] f32 (134M).
// Outside the +-128 window each attention row is one constant c = exp(-m)/den
// (reference zero-fills logits outside the band). Band via MFMA; the rest is
// filled with per-row constants at the tail of the same attention kernel.
// Pipeline: cvt_w (weights only) -> gemm_qkv (f32 x, fused cvt in staging)
//           -> attn(+fill) -> gemm_o.
// ---------------------------------------------------------------------------

typedef unsigned short u16;
typedef __bf16 bf16x8 __attribute__((ext_vector_type(8)));
typedef float  f32x4  __attribute__((ext_vector_type(4)));
typedef u16    u16x8  __attribute__((ext_vector_type(8)));

#define GLOAD_LDS(gsrc, ldst)                                                  \
    __builtin_amdgcn_global_load_lds(                                          \
        (const __attribute__((address_space(1))) void*)(gsrc),                 \
        (__attribute__((address_space(3))) void*)(ldst), 16, 0, 0)

__device__ __forceinline__ u16 f2bf(float f) {
    union { float f; unsigned u; } x; x.f = f;
    unsigned u = x.u;
    u += 0x7fffu + ((u >> 16) & 1u);   // round-to-nearest-even
    return (u16)(u >> 16);
}
__device__ __forceinline__ int swzc(int c, int r) {
    return (c < 32) ? (c ^ (r & 7)) : c;
}

// ---------------------------------------------------------------------------
// f32 -> bf16 for the 4 weight matrices only (4 x 512x512). grid = 1024.
// ---------------------------------------------------------------------------
struct CvtWArgs {
    const float* src[4];
    u16*         dst[4];
};

__global__ __launch_bounds__(256) void cvt_w(CvtWArgs a) {
    int t = blockIdx.x >> 8, blk = blockIdx.x & 255;
    int i = (blk * 256 + threadIdx.x) * 4;
    float4 v = *(const float4*)(a.src[t] + i);
    ushort4 o;
    o.x = f2bf(v.x); o.y = f2bf(v.y); o.z = f2bf(v.z); o.w = f2bf(v.w);
    *(ushort4*)(a.dst[t] + i) = o;
}

// ---------------------------------------------------------------------------
// QKV GEMM: Y[M,512] = X[M,512] @ W^T + b for q,k,v stacked. X is f32;
// conversion to bf16 is fused into A-staging (reg-staged, swizzled
// ds_write_b128). W is pre-converted bf16, staged via global_load_lds w16
// with source-side XOR swizzle. 128x128 tile, BK=64, grid (64,12), bn>>2
// selects tensor. V blocks (t==2) also accumulate column sums into sumv.
// ---------------------------------------------------------------------------
__global__ __launch_bounds__(256) void gemm_qkv(
    const float* __restrict__ A0, const float* __restrict__ A1, const float* __restrict__ A2,
    const u16* __restrict__ B,
    const float* __restrict__ b0, const float* __restrict__ b1, const float* __restrict__ b2,
    u16* __restrict__ o0, u16* __restrict__ o1, u16* __restrict__ o2,
    float* __restrict__ sumv)
{
    __shared__ __attribute__((aligned(16))) u16 As[128 * 64];
    __shared__ __attribute__((aligned(16))) u16 Bs[128 * 64];

    const int tid  = threadIdx.x;
    const int lane = tid & 63;
    const int w    = tid >> 6;
    const int bm   = blockIdx.x, bn = blockIdx.y;
    const int wm   = w >> 1, wn = w & 1;

    const int t = bn >> 2;
    const float* A = (t == 0) ? A0 : (t == 1) ? A1 : A2;
    const float* Ag = A + (size_t)bm * 128 * 512;
    const u16* Bg = B + (size_t)bn * 128 * 512;

    f32x4 acc[4][4];
#pragma unroll
    for (int m = 0; m < 4; ++m)
#pragma unroll
        for (int n = 0; n < 4; ++n) acc[m][n] = 0;

    const int swc = ((lane & 7) ^ (lane >> 3)) * 8;  // pre-swizzled source chunk (B)
    const int arow = tid >> 1, ahalf = tid & 1;      // A staging: 2 thr/row
    const float* asrc = Ag + (size_t)arow * 512 + ahalf * 32;

    for (int k0 = 0; k0 < 512; k0 += 64) {
        // ---- stage A (f32 -> bf16, swizzled write) ----
        float4 fv[8];
#pragma unroll
        for (int i = 0; i < 8; ++i) fv[i] = *(const float4*)(asrc + k0 + i * 4);
#pragma unroll
        for (int c4 = 0; c4 < 4; ++c4) {
            bf16x8 pk;
#pragma unroll
            for (int e = 0; e < 8; ++e) {
                float f = ((const float*)&fv[c4 * 2])[e];  // fv[c4*2], fv[c4*2+1]
                pk[e] = (__bf16)f;
            }
            int ch = ahalf * 4 + c4;
            *(bf16x8*)(As + arow * 64 + ((ch ^ (arow & 7)) * 8)) = pk;
        }
        // ---- stage B (global_load_lds w16) ----
#pragma unroll
        for (int i = 0; i < 4; ++i) {
            int g = i * 4 + w;
            GLOAD_LDS(Bg + (size_t)(g * 8 + (lane >> 3)) * 512 + k0 + swc, Bs + g * 512);
        }
        __syncthreads();

#pragma unroll
        for (int s = 0; s < 2; ++s) {
            bf16x8 af[4], bf[4];
            int c = s * 4 + (lane >> 4);
#pragma unroll
            for (int m = 0; m < 4; ++m) {
                int r = wm * 64 + m * 16 + (lane & 15);
                af[m] = *(const bf16x8*)(As + r * 64 + ((c ^ (r & 7)) * 8));
                int r2 = wn * 64 + m * 16 + (lane & 15);
                bf[m] = *(const bf16x8*)(Bs + r2 * 64 + ((c ^ (r2 & 7)) * 8));
            }
#pragma unroll
            for (int m = 0; m < 4; ++m)
#pragma unroll
                for (int n = 0; n < 4; ++n)
                    acc[m][n] = __builtin_amdgcn_mfma_f32_16x16x32_bf16(af[m], bf[n], acc[m][n], 0, 0, 0);
        }
        __syncthreads();
    }

    const float* bias = (t == 0) ? b0 : (t == 1) ? b1 : b2;
    u16* ob = (t == 0) ? o0 : (t == 1) ? o1 : o2;
    const int clbase = (bn & 3) * 128;

#pragma unroll
    for (int m = 0; m < 4; ++m) {
#pragma unroll
        for (int n = 0; n < 4; ++n) {
            int cl = clbase + wn * 64 + n * 16 + (lane & 15);
            float bb = bias[cl];
#pragma unroll
            for (int reg = 0; reg < 4; ++reg) {
                int row = bm * 128 + wm * 64 + m * 16 + (lane >> 4) * 4 + reg;
                ob[(size_t)row * 512 + cl] = f2bf(acc[m][n][reg] + bb);
            }
        }
    }

    // V-tensor blocks: column sums (this block's 128 rows) -> sumv[n][col]
    if (t == 2) {
        int nb = bm >> 4;                       // batch index (128 | 2048)
#pragma unroll
        for (int n = 0; n < 4; ++n) {
            float s = 0.f;
#pragma unroll
            for (int m = 0; m < 4; ++m)
#pragma unroll
                for (int reg = 0; reg < 4; ++reg) s += acc[m][n][reg];
            s += __shfl_xor(s, 16, 64);
            s += __shfl_xor(s, 32, 64);
            if (lane < 16) {
                int cl = clbase + wn * 64 + n * 16 + lane;
                atomicAdd(sumv + nb * 512 + cl, s);
            }
        }
    }
}

// ---------------------------------------------------------------------------
// Out projection: fo[8192,512] = A[8192,512] @ Wo^T + bo.  128x64 tile,
// grid (64,8) = 512 blocks (2/CU). 4 waves, wave tile 64x32 (4x2 frags).
// ---------------------------------------------------------------------------
__global__ __launch_bounds__(256) void gemm_o(
    const u16* __restrict__ A, const u16* __restrict__ B,
    const float* __restrict__ bias, float* __restrict__ fo)
{
    __shared__ __attribute__((aligned(16))) u16 As[128 * 64];
    __shared__ __attribute__((aligned(16))) u16 Bs[64 * 64];

    const int tid  = threadIdx.x;
    const int lane = tid & 63;
    const int w    = tid >> 6;
    const int bm   = blockIdx.x, bn = blockIdx.y;
    const int wm   = w >> 1, wn = w & 1;

    const u16* Ag = A + (size_t)bm * 128 * 512;
    const u16* Bg = B + (size_t)bn * 64 * 512;

    f32x4 acc[4][2];
#pragma unroll
    for (int m = 0; m < 4; ++m) { acc[m][0] = 0; acc[m][1] = 0; }

    const int swc = ((lane & 7) ^ (lane >> 3)) * 8;

    for (int k0 = 0; k0 < 512; k0 += 64) {
#pragma unroll
        for (int i = 0; i < 4; ++i) {
            int g = i * 4 + w;
            GLOAD_LDS(Ag + (size_t)(g * 8 + (lane >> 3)) * 512 + k0 + swc, As + g * 512);
        }
#pragma unroll
        for (int i = 0; i < 2; ++i) {
            int g = i * 4 + w;
            GLOAD_LDS(Bg + (size_t)(g * 8 + (lane >> 3)) * 512 + k0 + swc, Bs + g * 512);
        }
        __syncthreads();

#pragma unroll
        for (int s = 0; s < 2; ++s) {
            bf16x8 af[4], bf[2];
            int c = s * 4 + (lane >> 4);
#pragma unroll
            for (int m = 0; m < 4; ++m) {
                int r = wm * 64 + m * 16 + (lane & 15);
                af[m] = *(const bf16x8*)(As + r * 64 + ((c ^ (r & 7)) * 8));
            }
#pragma unroll
            for (int n = 0; n < 2; ++n) {
                int r2 = wn * 32 + n * 16 + (lane & 15);
                bf[n] = *(const bf16x8*)(Bs + r2 * 64 + ((c ^ (r2 & 7)) * 8));
            }
#pragma unroll
            for (int m = 0; m < 4; ++m)
#pragma unroll
                for (int n = 0; n < 2; ++n)
                    acc[m][n] = __builtin_amdgcn_mfma_f32_16x16x32_bf16(af[m], bf[n], acc[m][n], 0, 0, 0);
        }
        __syncthreads();
    }

#pragma unroll
    for (int m = 0; m < 4; ++m) {
#pragma unroll
        for (int n = 0; n < 2; ++n) {
            int cl = bn * 64 + wn * 32 + n * 16 + (lane & 15);
            float bb = bias[cl];
#pragma unroll
            for (int reg = 0; reg < 4; ++reg) {
                int row = bm * 128 + wm * 64 + m * 16 + (lane >> 4) * 4 + reg;
                fo[(size_t)row * 512 + cl] = acc[m][n][reg] + bb;
            }
        }
    }
}

// ---------------------------------------------------------------------------
// Fused windowed attention band + constant fill. One block = 32 query rows
// of one (n,h). K/Q staged via global_load_lds (linear LDS, source-side XOR
// swizzle; OOB rows clamped -- masked later). V transposed in LDS with
// chunk-XOR pjc = jc ^ ch (2-way write banks). XCD-chunked block swizzle.
// After PV, the same block fills everything outside its union band with the
// per-row constant c (float4 streaming stores).
// LDS: Qs/stats 4KB | Ks 36KB (aliased by A') | Vt [64][296] 37KB = 78.8KB.
// ---------------------------------------------------------------------------
__global__ __launch_bounds__(256) void attn_kernel(
    const u16* __restrict__ qb, const u16* __restrict__ kb,
    const u16* __restrict__ vb, const int* __restrict__ mask,
    const float* __restrict__ sumv, float* __restrict__ att,
    u16* __restrict__ oh) {
    __shared__ __attribute__((aligned(16))) char lds[78848];
    u16*   Qs      = (u16*)lds;            // [32][64] bf16, chunk-swizzled
    float* stat_m  = (float*)lds;          // [32]  (aliases Qs after scores)
    float* stat_rd = (float*)(lds + 128);  // [32]
    float* stat_c  = (float*)(lds + 256);  // [32]
    float* red     = (float*)(lds + 384);  // [4][16]
    float* red2    = (float*)(lds + 640);  // [4][16]
    u16*   Ks      = (u16*)(lds + 4096);   // [288][64] bf16, chunk-swizzled
    u16*   Ab      = Ks;                   // [32][288] bf16 (after scores)
    u16*   Vt      = (u16*)(lds + 4096 + 36864); // [64][296] bf16 transposed

    const int tid  = threadIdx.x;
    const int lane = tid & 63;
    const int w    = tid >> 6;
    const int bid0 = blockIdx.x;
    const int bid  = (bid0 & 7) * 256 + (bid0 >> 3);   // XCD-chunked swizzle
    const int tile = bid & 63;
    const int h    = (bid >> 6) & 7;
    const int n    = bid >> 9;
    const int i0   = tile * 32;
    const int jlo  = max(0, i0 - 128);
    const float scale = 0.04419417382415922f;  // 1/sqrt(512)

    const size_t base_nh = (size_t)n * 2048 * 512 + h * 64;
    const int lr = lane >> 3;              // row-in-group for staging
    const int swg = ((lane & 7) ^ lr) * 8; // source chunk (XOR swizzle)

    // ---- stage Qs [32][64] via global_load_lds (1 instr/wave) ----
    GLOAD_LDS(qb + base_nh + (size_t)(i0 + w * 8 + lr) * 512 + swg, Qs + w * 512);
    // ---- stage Ks [288][64] (rows >= 2048 clamped; masked later) ----
    for (int p = 0; p < 9; ++p) {
        int g = p * 4 + w;                 // row group 0..35
        int j = min(jlo + g * 8 + lr, 2047);
        GLOAD_LDS(kb + base_nh + (size_t)j * 512 + swg, Ks + g * 512);
    }
    // ---- stage Vt [64][296] = V^T; chunk-XOR write swizzle (2-way banks) ----
    for (int p = 0; p < 9; ++p) {
        int idx = p * 256 + tid;
        int jj = idx >> 3, ch = idx & 7;
        int j = jlo + jj;
        u16x8 tmp = {0, 0, 0, 0, 0, 0, 0, 0};
        if (j < 2048) tmp = *(const u16x8*)(vb + base_nh + (size_t)j * 512 + ch * 8);
        int jc = jj >> 3, jr = jj & 7;
        int pjc = (jc < 32) ? (jc ^ ch) : jc;
#pragma unroll
        for (int r = 0; r < 8; ++r)
            Vt[(ch * 8 + r) * 296 + pjc * 8 + jr] = tmp[r];
    }
    __syncthreads();

    // ---- scores: S[32][288] = Q . K^T, wave -> 16 rows x 144 cols ----
    const int rbase = (w & 1) * 16;
    const int cbase = (w >> 1) * 144;
    f32x4 acc[9];
#pragma unroll
    for (int f = 0; f < 9; ++f) acc[f] = 0;

    bf16x8 aq[2];
    {
        int r = rbase + (lane & 15);
#pragma unroll
        for (int ks = 0; ks < 2; ++ks) {
            int kc = ks * 4 + (lane >> 4);
            aq[ks] = *(const bf16x8*)(Qs + r * 64 + ((kc ^ (r & 7)) * 8));
        }
    }
#pragma unroll
    for (int f = 0; f < 9; ++f) {
        int jj = cbase + f * 16 + (lane & 15);
#pragma unroll
        for (int ks = 0; ks < 2; ++ks) {
            int kc = ks * 4 + (lane >> 4);
            bf16x8 bk_ = *(const bf16x8*)(Ks + jj * 64 + ((kc ^ (jj & 7)) * 8));
            acc[f] = __builtin_amdgcn_mfma_f32_16x16x32_bf16(aq[ks], bk_, acc[f], 0, 0, 0);
        }
    }
    __syncthreads();   // Qs/Ks reads done; stats/A' may alias

    // ---- pass 1: logits + per-row max ----
    const int rowg = (lane >> 4) * 4;
    f32x4 lv[9];
    float mx[4] = {-__builtin_inff(), -__builtin_inff(), -__builtin_inff(), -__builtin_inff()};
#pragma unroll
    for (int f = 0; f < 9; ++f) {
        int jj = cbase + f * 16 + (lane & 15);
        int j = jlo + jj;
        int mk = (j < 2048) ? mask[n * 2048 + j] : 0;
#pragma unroll
        for (int reg = 0; reg < 4; ++reg) {
            int i = i0 + rbase + rowg + reg;
            bool inw = (j >= i - 128) && (j <= i + 128) && (j < 2048);
            float val = (inw && mk != 0) ? acc[f][reg] * scale : -__builtin_inff();
            lv[f][reg] = val;
            mx[reg] = fmaxf(mx[reg], val);
        }
    }
#pragma unroll
    for (int mskk = 1; mskk < 16; mskk <<= 1)
#pragma unroll
        for (int reg = 0; reg < 4; ++reg)
            mx[reg] = fmaxf(mx[reg], __shfl_xor(mx[reg], mskk, 64));
    if ((lane & 15) == 0) {
#pragma unroll
        for (int reg = 0; reg < 4; ++reg) red[w * 16 + rowg + reg] = mx[reg];
    }
    __syncthreads();
    if (tid < 32) {
        int r = tid;
        int wa = (r < 16) ? 0 : 1, rr = r & 15;
        stat_m[r] = fmaxf(fmaxf(red[wa * 16 + rr], red[(wa + 2) * 16 + rr]), 0.0f);
    }
    __syncthreads();

    // ---- pass 2: denom ----
    float m4[4];
#pragma unroll
    for (int reg = 0; reg < 4; ++reg) m4[reg] = stat_m[rbase + rowg + reg];
    float sm[4] = {0, 0, 0, 0};
#pragma unroll
    for (int f = 0; f < 9; ++f)
#pragma unroll
        for (int reg = 0; reg < 4; ++reg)
            sm[reg] += __expf(lv[f][reg] - m4[reg]);
#pragma unroll
    for (int mskk = 1; mskk < 16; mskk <<= 1)
#pragma unroll
        for (int reg = 0; reg < 4; ++reg)
            sm[reg] += __shfl_xor(sm[reg], mskk, 64);
    if ((lane & 15) == 0) {
#pragma unroll
        for (int reg = 0; reg < 4; ++reg) red2[w * 16 + rowg + reg] = sm[reg];
    }
    __syncthreads();
    if (tid < 32) {
        int r = tid, gi = i0 + r;
        int wa = (r < 16) ? 0 : 1, rr = r & 15;
        float s = red2[wa * 16 + rr] + red2[(wa + 2) * 16 + rr];
        int lo = max(0, gi - 128), hi = min(2048, gi + 129);
        float em = __expf(-stat_m[r]);
        float denom = s + (float)(2048 - (hi - lo)) * em;
        float rd = 1.0f / denom;
        stat_rd[r] = rd;
        stat_c[r] = em * rd;
    }
    __syncthreads();

    // ---- pass 3: band attention writes + A' = (att - c) bf16 in LDS ----
    float rd4[4], c4[4];
#pragma unroll
    for (int reg = 0; reg < 4; ++reg) {
        rd4[reg] = stat_rd[rbase + rowg + reg];
        c4[reg] = stat_c[rbase + rowg + reg];
    }
#pragma unroll
    for (int f = 0; f < 9; ++f) {
        int jj = cbase + f * 16 + (lane & 15);
        int j = jlo + jj;
        int jc = jj >> 3;
#pragma unroll
        for (int reg = 0; reg < 4; ++reg) {
            int it = rbase + rowg + reg;
            int i = i0 + it;
            bool inw = (j >= i - 128) && (j <= i + 128) && (j < 2048);
            float e = __expf(lv[f][reg] - m4[reg]);
            float a = inw ? e * rd4[reg] : c4[reg];
            if (j < 2048)
                att[((size_t)(n * 8 + h) * 2048 + i) * 2048 + j] = a;
            float ab = inw ? (a - c4[reg]) : 0.0f;
            ((u16*)((char*)Ab + it * 576 + (swzc(jc, it) << 4)))[jj & 7] = f2bf(ab);
        }
    }
    __syncthreads();

    // ---- PV: out[32][64] = A'[32][288] @ V[288][64] (via Vt), + c*sumv ----
    const int rb2 = (w & 1) * 16;
    const int db  = (w >> 1) * 32;
    f32x4 po[2];
    po[0] = 0; po[1] = 0;
#pragma unroll
    for (int ks = 0; ks < 9; ++ks) {
        int kc = ks * 4 + (lane >> 4);
        int it = rb2 + (lane & 15);
        bf16x8 af = *(const bf16x8*)((char*)Ab + it * 576 + (swzc(kc, it) << 4));
#pragma unroll
        for (int f = 0; f < 2; ++f) {
            int d = db + f * 16 + (lane & 15);
            int phys = (kc < 32) ? (kc ^ (d >> 3)) : kc;
            bf16x8 bv_ = *(const bf16x8*)(Vt + d * 296 + phys * 8);
            po[f] = __builtin_amdgcn_mfma_f32_16x16x32_bf16(af, bv_, po[f], 0, 0, 0);
        }
    }
    {
        const float* svp = sumv + (size_t)n * 512 + h * 64;
#pragma unroll
        for (int f = 0; f < 2; ++f) {
            int d = db + f * 16 + (lane & 15);
            float sv = svp[d];
#pragma unroll
            for (int reg = 0; reg < 4; ++reg) {
                int it = rb2 + rowg + reg;
                float val = po[f][reg] + stat_c[it] * sv;
                oh[base_nh + (size_t)(i0 + it) * 512 + d] = f2bf(val);
            }
        }
    }

    // ---- tail: fill outside-band with per-row c (float4 streaming) ----
    {
        int jend = min(2048, jlo + 288);
        int j4lo = jlo >> 2, j4end = jend >> 2;
        size_t rowbase = ((size_t)(n * 8 + h) * 2048 + i0) * 2048;
        for (int idx = tid; idx < 32 * 512; idx += 256) {
            int r = idx >> 9, j4 = idx & 511;
            if (j4 >= j4lo && j4 < j4end) continue;
            float c = stat_c[r];
            *(float4*)(att + rowbase + (size_t)r * 2048 + j4 * 4) = make_float4(c, c, c, c);
        }
    }
}

// ---------------------------------------------------------------------------
extern "C" void kernel_launch(void* const* d_in, const int* in_sizes, int n_in,
                              void* d_out, int out_size, void* d_ws, size_t ws_size,
                              hipStream_t stream) {
    const float* value = (const float*)d_in[0];
    const float* key_  = (const float*)d_in[1];
    const float* query = (const float*)d_in[2];
    const int*   mask  = (const int*)d_in[3];
    const float* Wv = (const float*)d_in[4];
    const float* bv = (const float*)d_in[5];
    const float* Wk = (const float*)d_in[6];
    const float* bk = (const float*)d_in[7];
    const float* Wq = (const float*)d_in[8];
    const float* bq = (const float*)d_in[9];
    const float* Wo = (const float*)d_in[10];
    const float* bo = (const float*)d_in[11];

    char* ws = (char*)d_ws;
    size_t off = 0;
    auto carve = [&](size_t bytes) -> char* {
        char* p = ws + off;
        off += (bytes + 255) & ~(size_t)255;
        return p;
    };
    const size_t XB = (size_t)8192 * 512 * 2;   // bf16 [8192,512]
    const size_t WB = (size_t)512 * 512 * 2;    // bf16 [512,512]
    u16* wqkv = (u16*)carve(3 * WB);            // [1536,512]: Wq rows, Wk, Wv
    u16* wob  = (u16*)carve(WB);
    u16* qb   = (u16*)carve(XB);
    u16* kb   = (u16*)carve(XB);
    u16* vb2  = (u16*)carve(XB);
    u16* ohb  = (u16*)carve(XB);
    float* sumv = (float*)carve(2048 * sizeof(float));

    hipMemsetAsync(sumv, 0, 2048 * sizeof(float), stream);

    CvtWArgs ca;
    ca.src[0] = Wq; ca.dst[0] = wqkv;
    ca.src[1] = Wk; ca.dst[1] = wqkv + (size_t)512 * 512;
    ca.src[2] = Wv; ca.dst[2] = wqkv + (size_t)1024 * 512;
    ca.src[3] = Wo; ca.dst[3] = wob;

    cvt_w<<<dim3(1024), 256, 0, stream>>>(ca);
    gemm_qkv<<<dim3(64, 12), 256, 0, stream>>>(
        query, key_, value, wqkv, bq, bk, bv, qb, kb, vb2, sumv);

    float* att = (float*)d_out + (size_t)4 * 2048 * 512;
    attn_kernel<<<dim3(2048), 256, 0, stream>>>(qb, kb, vb2, mask, sumv, att, ohb);
    gemm_o<<<dim3(64, 8), 256, 0, stream>>>(ohb, wob, bo, (float*)d_out);
}

// Round 7
// 643.586 us; speedup vs baseline: 1.2608x; 1.0308x over previous
//
#include <hip/hip_runtime.h>

// ---------------------------------------------------------------------------
// WindowedSelfAttention: N=4, S=2048, E=512, H=8, D=64, WIN=256
// d_out: out [N,S,E] f32 (4.19M) then att [N,H,S,S] f32 (134M).
// Outside the +-128 window each attention row is one constant c = exp(-m)/den
// (reference zero-fills logits outside the band). Band via MFMA; A'=(att-c)
// kept in f32 LDS; one streaming tail writes full att rows (A'+c / c).
// Pipeline: cvt_w (weights) -> gemm_qkv (f32 x, fused cvt) -> attn -> gemm_o.
// ---------------------------------------------------------------------------

typedef unsigned short u16;
typedef __bf16 bf16x8 __attribute__((ext_vector_type(8)));
typedef float  f32x4  __attribute__((ext_vector_type(4)));
typedef u16    u16x8  __attribute__((ext_vector_type(8)));

#define GLOAD_LDS(gsrc, ldst)                                                  \
    __builtin_amdgcn_global_load_lds(                                          \
        (const __attribute__((address_space(1))) void*)(gsrc),                 \
        (__attribute__((address_space(3))) void*)(ldst), 16, 0, 0)

__device__ __forceinline__ u16 f2bf(float f) {
    union { float f; unsigned u; } x; x.f = f;
    unsigned u = x.u;
    u += 0x7fffu + ((u >> 16) & 1u);   // round-to-nearest-even
    return (u16)(u >> 16);
}

// ---------------------------------------------------------------------------
// f32 -> bf16 for the 4 weight matrices only (4 x 512x512). grid = 1024.
// ---------------------------------------------------------------------------
struct CvtWArgs {
    const float* src[4];
    u16*         dst[4];
};

__global__ __launch_bounds__(256) void cvt_w(CvtWArgs a) {
    int t = blockIdx.x >> 8, blk = blockIdx.x & 255;
    int i = (blk * 256 + threadIdx.x) * 4;
    float4 v = *(const float4*)(a.src[t] + i);
    ushort4 o;
    o.x = f2bf(v.x); o.y = f2bf(v.y); o.z = f2bf(v.z); o.w = f2bf(v.w);
    *(ushort4*)(a.dst[t] + i) = o;
}

// ---------------------------------------------------------------------------
// QKV GEMM: Y[M,512] = X[M,512] @ W^T + b for q,k,v stacked. X is f32;
// conversion to bf16 fused into A-staging (reg-staged, swizzled ds_write).
// W bf16 staged via global_load_lds w16 + source-side XOR swizzle.
// 128x128 tile, BK=64, grid (64,12), bn>>2 selects tensor. V blocks (t==2)
// also accumulate column sums into sumv (atomicAdd; sumv pre-zeroed).
// ---------------------------------------------------------------------------
__global__ __launch_bounds__(256) void gemm_qkv(
    const float* __restrict__ A0, const float* __restrict__ A1, const float* __restrict__ A2,
    const u16* __restrict__ B,
    const float* __restrict__ b0, const float* __restrict__ b1, const float* __restrict__ b2,
    u16* __restrict__ o0, u16* __restrict__ o1, u16* __restrict__ o2,
    float* __restrict__ sumv)
{
    __shared__ __attribute__((aligned(16))) u16 As[128 * 64];
    __shared__ __attribute__((aligned(16))) u16 Bs[128 * 64];

    const int tid  = threadIdx.x;
    const int lane = tid & 63;
    const int w    = tid >> 6;
    const int bm   = blockIdx.x, bn = blockIdx.y;
    const int wm   = w >> 1, wn = w & 1;

    const int t = bn >> 2;
    const float* A = (t == 0) ? A0 : (t == 1) ? A1 : A2;
    const float* Ag = A + (size_t)bm * 128 * 512;
    const u16* Bg = B + (size_t)bn * 128 * 512;

    f32x4 acc[4][4];
#pragma unroll
    for (int m = 0; m < 4; ++m)
#pragma unroll
        for (int n = 0; n < 4; ++n) acc[m][n] = 0;

    const int swc = ((lane & 7) ^ (lane >> 3)) * 8;  // pre-swizzled source chunk (B)
    const int arow = tid >> 1, ahalf = tid & 1;      // A staging: 2 thr/row
    const float* asrc = Ag + (size_t)arow * 512 + ahalf * 32;

    for (int k0 = 0; k0 < 512; k0 += 64) {
        // ---- stage A (f32 -> bf16, swizzled write) ----
        float4 fv[8];
#pragma unroll
        for (int i = 0; i < 8; ++i) fv[i] = *(const float4*)(asrc + k0 + i * 4);
#pragma unroll
        for (int c4 = 0; c4 < 4; ++c4) {
            bf16x8 pk;
#pragma unroll
            for (int e = 0; e < 8; ++e) {
                float f = ((const float*)&fv[c4 * 2])[e];
                pk[e] = (__bf16)f;
            }
            int ch = ahalf * 4 + c4;
            *(bf16x8*)(As + arow * 64 + ((ch ^ (arow & 7)) * 8)) = pk;
        }
        // ---- stage B (global_load_lds w16) ----
#pragma unroll
        for (int i = 0; i < 4; ++i) {
            int g = i * 4 + w;
            GLOAD_LDS(Bg + (size_t)(g * 8 + (lane >> 3)) * 512 + k0 + swc, Bs + g * 512);
        }
        __syncthreads();

#pragma unroll
        for (int s = 0; s < 2; ++s) {
            bf16x8 af[4], bf[4];
            int c = s * 4 + (lane >> 4);
#pragma unroll
            for (int m = 0; m < 4; ++m) {
                int r = wm * 64 + m * 16 + (lane & 15);
                af[m] = *(const bf16x8*)(As + r * 64 + ((c ^ (r & 7)) * 8));
                int r2 = wn * 64 + m * 16 + (lane & 15);
                bf[m] = *(const bf16x8*)(Bs + r2 * 64 + ((c ^ (r2 & 7)) * 8));
            }
#pragma unroll
            for (int m = 0; m < 4; ++m)
#pragma unroll
                for (int n = 0; n < 4; ++n)
                    acc[m][n] = __builtin_amdgcn_mfma_f32_16x16x32_bf16(af[m], bf[n], acc[m][n], 0, 0, 0);
        }
        __syncthreads();
    }

    const float* bias = (t == 0) ? b0 : (t == 1) ? b1 : b2;
    u16* ob = (t == 0) ? o0 : (t == 1) ? o1 : o2;
    const int clbase = (bn & 3) * 128;

#pragma unroll
    for (int m = 0; m < 4; ++m) {
#pragma unroll
        for (int n = 0; n < 4; ++n) {
            int cl = clbase + wn * 64 + n * 16 + (lane & 15);
            float bb = bias[cl];
#pragma unroll
            for (int reg = 0; reg < 4; ++reg) {
                int row = bm * 128 + wm * 64 + m * 16 + (lane >> 4) * 4 + reg;
                ob[(size_t)row * 512 + cl] = f2bf(acc[m][n][reg] + bb);
            }
        }
    }

    // V-tensor blocks: column sums (this block's 128 rows) -> sumv[n][col]
    if (t == 2) {
        int nb = bm >> 4;                       // batch index (128 | 2048)
#pragma unroll
        for (int n = 0; n < 4; ++n) {
            float s = 0.f;
#pragma unroll
            for (int m = 0; m < 4; ++m)
#pragma unroll
                for (int reg = 0; reg < 4; ++reg) s += acc[m][n][reg];
            s += __shfl_xor(s, 16, 64);
            s += __shfl_xor(s, 32, 64);
            if (lane < 16) {
                int cl = clbase + wn * 64 + n * 16 + lane;
                atomicAdd(sumv + nb * 512 + cl, s);
            }
        }
    }
}

// ---------------------------------------------------------------------------
// Out projection: fo[8192,512] = A[8192,512] @ Wo^T + bo.  128x64 tile,
// grid (64,8) = 512 blocks (2/CU). 4 waves, wave tile 64x32 (4x2 frags).
// ---------------------------------------------------------------------------
__global__ __launch_bounds__(256) void gemm_o(
    const u16* __restrict__ A, const u16* __restrict__ B,
    const float* __restrict__ bias, float* __restrict__ fo)
{
    __shared__ __attribute__((aligned(16))) u16 As[128 * 64];
    __shared__ __attribute__((aligned(16))) u16 Bs[64 * 64];

    const int tid  = threadIdx.x;
    const int lane = tid & 63;
    const int w    = tid >> 6;
    const int bm   = blockIdx.x, bn = blockIdx.y;
    const int wm   = w >> 1, wn = w & 1;

    const u16* Ag = A + (size_t)bm * 128 * 512;
    const u16* Bg = B + (size_t)bn * 64 * 512;

    f32x4 acc[4][2];
#pragma unroll
    for (int m = 0; m < 4; ++m) { acc[m][0] = 0; acc[m][1] = 0; }

    const int swc = ((lane & 7) ^ (lane >> 3)) * 8;

    for (int k0 = 0; k0 < 512; k0 += 64) {
#pragma unroll
        for (int i = 0; i < 4; ++i) {
            int g = i * 4 + w;
            GLOAD_LDS(Ag + (size_t)(g * 8 + (lane >> 3)) * 512 + k0 + swc, As + g * 512);
        }
#pragma unroll
        for (int i = 0; i < 2; ++i) {
            int g = i * 4 + w;
            GLOAD_LDS(Bg + (size_t)(g * 8 + (lane >> 3)) * 512 + k0 + swc, Bs + g * 512);
        }
        __syncthreads();

#pragma unroll
        for (int s = 0; s < 2; ++s) {
            bf16x8 af[4], bf[2];
            int c = s * 4 + (lane >> 4);
#pragma unroll
            for (int m = 0; m < 4; ++m) {
                int r = wm * 64 + m * 16 + (lane & 15);
                af[m] = *(const bf16x8*)(As + r * 64 + ((c ^ (r & 7)) * 8));
            }
#pragma unroll
            for (int n = 0; n < 2; ++n) {
                int r2 = wn * 32 + n * 16 + (lane & 15);
                bf[n] = *(const bf16x8*)(Bs + r2 * 64 + ((c ^ (r2 & 7)) * 8));
            }
#pragma unroll
            for (int m = 0; m < 4; ++m)
#pragma unroll
                for (int n = 0; n < 2; ++n)
                    acc[m][n] = __builtin_amdgcn_mfma_f32_16x16x32_bf16(af[m], bf[n], acc[m][n], 0, 0, 0);
        }
        __syncthreads();
    }

#pragma unroll
    for (int m = 0; m < 4; ++m) {
#pragma unroll
        for (int n = 0; n < 2; ++n) {
            int cl = bn * 64 + wn * 32 + n * 16 + (lane & 15);
            float bb = bias[cl];
#pragma unroll
            for (int reg = 0; reg < 4; ++reg) {
                int row = bm * 128 + wm * 64 + m * 16 + (lane >> 4) * 4 + reg;
                fo[(size_t)row * 512 + cl] = acc[m][n][reg] + bb;
            }
        }
    }
}

// ---------------------------------------------------------------------------
// Fused windowed attention. One block = 32 query rows of one (n,h).
// K/Q staged via global_load_lds (linear LDS, source-side XOR swizzle).
// V transposed in LDS (chunk-XOR write swizzle). Scores via MFMA; softmax
// stats via shfl; A' = (att - c) stored as f32 in LDS [32][292] (pad 292 ->
// 2-way banks, aliases Ks); PV reads A' + converts to bf16 in-register;
// tail streams FULL att rows: att[j] = A'[j-jlo] + c in-band, c outside --
// perfectly coalesced f32x4 nontemporal stores (no scattered band writes).
// LDS: Qs/stats 4KB | A'/Ks 37.6KB | Vt [64][296] 37.9KB = 79.6KB (2/CU).
// ---------------------------------------------------------------------------
__global__ __launch_bounds__(256) void attn_kernel(
    const u16* __restrict__ qb, const u16* __restrict__ kb,
    const u16* __restrict__ vb, const int* __restrict__ mask,
    const float* __restrict__ sumv, float* __restrict__ att,
    u16* __restrict__ oh) {
    __shared__ __attribute__((aligned(16))) char lds[79616];
    u16*   Qs      = (u16*)lds;            // [32][64] bf16, chunk-swizzled
    float* stat_m  = (float*)lds;          // [32]  (aliases Qs after scores)
    float* stat_rd = (float*)(lds + 128);  // [32]
    float* stat_c  = (float*)(lds + 256);  // [32]
    float* red     = (float*)(lds + 384);  // [4][16]
    float* red2    = (float*)(lds + 640);  // [4][16]
    u16*   Ks      = (u16*)(lds + 4096);   // [288][64] bf16 (scores phase)
    float* Ab32    = (float*)(lds + 4096); // [32][292] f32 A' (after scores)
    u16*   Vt      = (u16*)(lds + 4096 + 37632); // [64][296] bf16 transposed

    const int tid  = threadIdx.x;
    const int lane = tid & 63;
    const int w    = tid >> 6;
    const int bid0 = blockIdx.x;
    const int bid  = (bid0 & 7) * 256 + (bid0 >> 3);   // XCD-chunked swizzle
    const int tile = bid & 63;
    const int h    = (bid >> 6) & 7;
    const int n    = bid >> 9;
    const int i0   = tile * 32;
    const int jlo  = max(0, i0 - 128);
    const float scale = 0.04419417382415922f;  // 1/sqrt(512)

    const size_t base_nh = (size_t)n * 2048 * 512 + h * 64;
    const int lr = lane >> 3;              // row-in-group for staging
    const int swg = ((lane & 7) ^ lr) * 8; // source chunk (XOR swizzle)

    // ---- stage Qs [32][64] via global_load_lds (1 instr/wave) ----
    GLOAD_LDS(qb + base_nh + (size_t)(i0 + w * 8 + lr) * 512 + swg, Qs + w * 512);
    // ---- stage Ks [288][64] (rows >= 2048 clamped; masked later) ----
    for (int p = 0; p < 9; ++p) {
        int g = p * 4 + w;                 // row group 0..35
        int j = min(jlo + g * 8 + lr, 2047);
        GLOAD_LDS(kb + base_nh + (size_t)j * 512 + swg, Ks + g * 512);
    }
    // ---- stage Vt [64][296] = V^T; chunk-XOR write swizzle (2-way banks) ----
    for (int p = 0; p < 9; ++p) {
        int idx = p * 256 + tid;
        int jj = idx >> 3, ch = idx & 7;
        int j = jlo + jj;
        u16x8 tmp = {0, 0, 0, 0, 0, 0, 0, 0};
        if (j < 2048) tmp = *(const u16x8*)(vb + base_nh + (size_t)j * 512 + ch * 8);
        int jc = jj >> 3, jr = jj & 7;
        int pjc = (jc < 32) ? (jc ^ ch) : jc;
#pragma unroll
        for (int r = 0; r < 8; ++r)
            Vt[(ch * 8 + r) * 296 + pjc * 8 + jr] = tmp[r];
    }
    __syncthreads();

    // ---- scores: S[32][288] = Q . K^T, wave -> 16 rows x 144 cols ----
    const int rbase = (w & 1) * 16;
    const int cbase = (w >> 1) * 144;
    f32x4 acc[9];
#pragma unroll
    for (int f = 0; f < 9; ++f) acc[f] = 0;

    bf16x8 aq[2];
    {
        int r = rbase + (lane & 15);
#pragma unroll
        for (int ks = 0; ks < 2; ++ks) {
            int kc = ks * 4 + (lane >> 4);
            aq[ks] = *(const bf16x8*)(Qs + r * 64 + ((kc ^ (r & 7)) * 8));
        }
    }
#pragma unroll
    for (int f = 0; f < 9; ++f) {
        int jj = cbase + f * 16 + (lane & 15);
#pragma unroll
        for (int ks = 0; ks < 2; ++ks) {
            int kc = ks * 4 + (lane >> 4);
            bf16x8 bk_ = *(const bf16x8*)(Ks + jj * 64 + ((kc ^ (jj & 7)) * 8));
            acc[f] = __builtin_amdgcn_mfma_f32_16x16x32_bf16(aq[ks], bk_, acc[f], 0, 0, 0);
        }
    }
    __syncthreads();   // Qs/Ks reads done; stats/A' may alias

    // ---- pass 1: logits + per-row max ----
    const int rowg = (lane >> 4) * 4;
    f32x4 lv[9];
    float mx[4] = {-__builtin_inff(), -__builtin_inff(), -__builtin_inff(), -__builtin_inff()};
#pragma unroll
    for (int f = 0; f < 9; ++f) {
        int jj = cbase + f * 16 + (lane & 15);
        int j = jlo + jj;
        int mk = (j < 2048) ? mask[n * 2048 + j] : 0;
#pragma unroll
        for (int reg = 0; reg < 4; ++reg) {
            int i = i0 + rbase + rowg + reg;
            bool inw = (j >= i - 128) && (j <= i + 128) && (j < 2048);
            float val = (inw && mk != 0) ? acc[f][reg] * scale : -__builtin_inff();
            lv[f][reg] = val;
            mx[reg] = fmaxf(mx[reg], val);
        }
    }
#pragma unroll
    for (int mskk = 1; mskk < 16; mskk <<= 1)
#pragma unroll
        for (int reg = 0; reg < 4; ++reg)
            mx[reg] = fmaxf(mx[reg], __shfl_xor(mx[reg], mskk, 64));
    if ((lane & 15) == 0) {
#pragma unroll
        for (int reg = 0; reg < 4; ++reg) red[w * 16 + rowg + reg] = mx[reg];
    }
    __syncthreads();
    if (tid < 32) {
        int r = tid;
        int wa = (r < 16) ? 0 : 1, rr = r & 15;
        stat_m[r] = fmaxf(fmaxf(red[wa * 16 + rr], red[(wa + 2) * 16 + rr]), 0.0f);
    }
    __syncthreads();

    // ---- pass 2: denom ----
    float m4[4];
#pragma unroll
    for (int reg = 0; reg < 4; ++reg) m4[reg] = stat_m[rbase + rowg + reg];
    float sm[4] = {0, 0, 0, 0};
#pragma unroll
    for (int f = 0; f < 9; ++f)
#pragma unroll
        for (int reg = 0; reg < 4; ++reg)
            sm[reg] += __expf(lv[f][reg] - m4[reg]);
#pragma unroll
    for (int mskk = 1; mskk < 16; mskk <<= 1)
#pragma unroll
        for (int reg = 0; reg < 4; ++reg)
            sm[reg] += __shfl_xor(sm[reg], mskk, 64);
    if ((lane & 15) == 0) {
#pragma unroll
        for (int reg = 0; reg < 4; ++reg) red2[w * 16 + rowg + reg] = sm[reg];
    }
    __syncthreads();
    if (tid < 32) {
        int r = tid, gi = i0 + r;
        int wa = (r < 16) ? 0 : 1, rr = r & 15;
        float s = red2[wa * 16 + rr] + red2[(wa + 2) * 16 + rr];
        int lo = max(0, gi - 128), hi = min(2048, gi + 129);
        float em = __expf(-stat_m[r]);
        float denom = s + (float)(2048 - (hi - lo)) * em;
        float rd = 1.0f / denom;
        stat_rd[r] = rd;
        stat_c[r] = em * rd;
    }
    __syncthreads();

    // ---- pass 3: A' = (att - c) f32 -> LDS [32][292] (no global writes) ----
    float rd4[4], c4[4];
#pragma unroll
    for (int reg = 0; reg < 4; ++reg) {
        rd4[reg] = stat_rd[rbase + rowg + reg];
        c4[reg] = stat_c[rbase + rowg + reg];
    }
#pragma unroll
    for (int f = 0; f < 9; ++f) {
        int jj = cbase + f * 16 + (lane & 15);
        int j = jlo + jj;
#pragma unroll
        for (int reg = 0; reg < 4; ++reg) {
            int it = rbase + rowg + reg;
            int i = i0 + it;
            bool inw = (j >= i - 128) && (j <= i + 128) && (j < 2048);
            float e = __expf(lv[f][reg] - m4[reg]);
            Ab32[it * 292 + jj] = inw ? (e * rd4[reg] - c4[reg]) : 0.0f;
        }
    }
    __syncthreads();

    // ---- PV: out[32][64] = A'[32][288] @ V[288][64] (via Vt), + c*sumv ----
    const int rb2 = (w & 1) * 16;
    const int db  = (w >> 1) * 32;
    f32x4 po[2];
    po[0] = 0; po[1] = 0;
#pragma unroll
    for (int ks = 0; ks < 9; ++ks) {
        int kc = ks * 4 + (lane >> 4);
        int it = rb2 + (lane & 15);
        const float* ap = Ab32 + it * 292 + kc * 8;
        float4 alo = *(const float4*)(ap);
        float4 ahi = *(const float4*)(ap + 4);
        bf16x8 af;
        af[0] = (__bf16)alo.x; af[1] = (__bf16)alo.y;
        af[2] = (__bf16)alo.z; af[3] = (__bf16)alo.w;
        af[4] = (__bf16)ahi.x; af[5] = (__bf16)ahi.y;
        af[6] = (__bf16)ahi.z; af[7] = (__bf16)ahi.w;
#pragma unroll
        for (int f = 0; f < 2; ++f) {
            int d = db + f * 16 + (lane & 15);
            int phys = (kc < 32) ? (kc ^ (d >> 3)) : kc;
            bf16x8 bv_ = *(const bf16x8*)(Vt + d * 296 + phys * 8);
            po[f] = __builtin_amdgcn_mfma_f32_16x16x32_bf16(af, bv_, po[f], 0, 0, 0);
        }
    }
    {
        const float* svp = sumv + (size_t)n * 512 + h * 64;
#pragma unroll
        for (int f = 0; f < 2; ++f) {
            int d = db + f * 16 + (lane & 15);
            float sv = svp[d];
#pragma unroll
            for (int reg = 0; reg < 4; ++reg) {
                int it = rb2 + rowg + reg;
                float val = po[f][reg] + stat_c[it] * sv;
                oh[base_nh + (size_t)(i0 + it) * 512 + d] = f2bf(val);
            }
        }
    }

    // ---- tail: stream FULL att rows (A'+c in-band, c outside), NT f32x4 ----
    {
        int jend = min(2048, jlo + 288);
        size_t rowbase = ((size_t)(n * 8 + h) * 2048 + i0) * 2048;
        for (int idx = tid; idx < 32 * 512; idx += 256) {
            int r = idx >> 9, j4 = idx & 511;
            int j = j4 * 4;
            float c = stat_c[r];
            f32x4 v = {c, c, c, c};
            if (j >= jlo && j < jend) {
                const float* ap = Ab32 + r * 292 + (j - jlo);
                v[0] += ap[0]; v[1] += ap[1]; v[2] += ap[2]; v[3] += ap[3];
            }
            __builtin_nontemporal_store(v, (f32x4*)(att + rowbase + (size_t)r * 2048 + j));
        }
    }
}

// ---------------------------------------------------------------------------
extern "C" void kernel_launch(void* const* d_in, const int* in_sizes, int n_in,
                              void* d_out, int out_size, void* d_ws, size_t ws_size,
                              hipStream_t stream) {
    const float* value = (const float*)d_in[0];
    const float* key_  = (const float*)d_in[1];
    const float* query = (const float*)d_in[2];
    const int*   mask  = (const int*)d_in[3];
    const float* Wv = (const float*)d_in[4];
    const float* bv = (const float*)d_in[5];
    const float* Wk = (const float*)d_in[6];
    const float* bk = (const float*)d_in[7];
    const float* Wq = (const float*)d_in[8];
    const float* bq = (const float*)d_in[9];
    const float* Wo = (const float*)d_in[10];
    const float* bo = (const float*)d_in[11];

    char* ws = (char*)d_ws;
    size_t off = 0;
    auto carve = [&](size_t bytes) -> char* {
        char* p = ws + off;
        off += (bytes + 255) & ~(size_t)255;
        return p;
    };
    const size_t XB = (size_t)8192 * 512 * 2;   // bf16 [8192,512]
    const size_t WB = (size_t)512 * 512 * 2;    // bf16 [512,512]
    u16* wqkv = (u16*)carve(3 * WB);            // [1536,512]: Wq rows, Wk, Wv
    u16* wob  = (u16*)carve(WB);
    u16* qb   = (u16*)carve(XB);
    u16* kb   = (u16*)carve(XB);
    u16* vb2  = (u16*)carve(XB);
    u16* ohb  = (u16*)carve(XB);
    float* sumv = (float*)carve(2048 * sizeof(float));

    (void)hipMemsetAsync(sumv, 0, 2048 * sizeof(float), stream);

    CvtWArgs ca;
    ca.src[0] = Wq; ca.dst[0] = wqkv;
    ca.src[1] = Wk; ca.dst[1] = wqkv + (size_t)512 * 512;
    ca.src[2] = Wv; ca.dst[2] = wqkv + (size_t)1024 * 512;
    ca.src[3] = Wo; ca.dst[3] = wob;

    cvt_w<<<dim3(1024), 256, 0, stream>>>(ca);
    gemm_qkv<<<dim3(64, 12), 256, 0, stream>>>(
        query, key_, value, wqkv, bq, bk, bv, qb, kb, vb2, sumv);

    float* att = (float*)d_out + (size_t)4 * 2048 * 512;
    attn_kernel<<<dim3(2048), 256, 0, stream>>>(qb, kb, vb2, mask, sumv, att, ohb);
    gemm_o<<<dim3(64, 8), 256, 0, stream>>>(ohb, wob, bo, (float*)d_out);
}

// Round 9
// 631.852 us; speedup vs baseline: 1.2842x; 1.0186x over previous
//
#include <hip/hip_runtime.h>

// ---------------------------------------------------------------------------
// WindowedSelfAttention: N=4, S=2048, E=512, H=8, D=64, WIN=256
// d_out: out [N,S,E] f32 (4.19M) then att [N,H,S,S] f32 (134M).
// Outside the +-128 window each attention row is one constant c = exp(-m)/den
// (reference zero-fills logits outside the band). Band via MFMA; A'=(att-c)
// in f32 LDS. Outside-band c-fill streams right after softmax stats (before
// PV) so the dominant 460 MB write overlaps compute; band rows after PV.
// Pipeline: cvt_w(+sumv zero) -> gemm_qkv (f32 x, fused cvt, coalesced +
// prefetch staging) -> attn -> gemm_o.
// ---------------------------------------------------------------------------

typedef unsigned short u16;
typedef __bf16 bf16x8 __attribute__((ext_vector_type(8)));
typedef float  f32x4  __attribute__((ext_vector_type(4)));
typedef u16    u16x8  __attribute__((ext_vector_type(8)));

#define GLOAD_LDS(gsrc, ldst)                                                  \
    __builtin_amdgcn_global_load_lds(                                          \
        (const __attribute__((address_space(1))) void*)(gsrc),                 \
        (__attribute__((address_space(3))) void*)(ldst), 16, 0, 0)

__device__ __forceinline__ u16 f2bf(float f) {
    union { float f; unsigned u; } x; x.f = f;
    unsigned u = x.u;
    u += 0x7fffu + ((u >> 16) & 1u);   // round-to-nearest-even
    return (u16)(u >> 16);
}

// ---------------------------------------------------------------------------
// f32 -> bf16 for the 4 weight matrices (4 x 512x512), grid = 1024.
// Block 0 additionally zeroes sumv (replaces a hipMemsetAsync dispatch).
// ---------------------------------------------------------------------------
struct CvtWArgs {
    const float* src[4];
    u16*         dst[4];
};

__global__ __launch_bounds__(256) void cvt_w(CvtWArgs a, float* __restrict__ sumv) {
    int t = blockIdx.x >> 8, blk = blockIdx.x & 255;
    int i = (blk * 256 + threadIdx.x) * 4;
    float4 v = *(const float4*)(a.src[t] + i);
    ushort4 o;
    o.x = f2bf(v.x); o.y = f2bf(v.y); o.z = f2bf(v.z); o.w = f2bf(v.w);
    *(ushort4*)(a.dst[t] + i) = o;
    if (blockIdx.x == 0) {
        for (int k = threadIdx.x; k < 2048; k += 256) sumv[k] = 0.f;
    }
}

// ---------------------------------------------------------------------------
// QKV GEMM: Y[M,512] = X[M,512] @ W^T + b for q,k,v stacked. X is f32;
// A-staging: 16 threads/row (wave = 4 rows x 256B contiguous -> clean
// coalescing), f32->bf16 cvt in regs, ushort4 swizzled ds_write; next
// K-tile's A prefetched into regs after the barrier (hides under MFMA).
// W bf16 staged via global_load_lds w16 + source-side XOR swizzle.
// 128x128 tile, BK=64, grid (64,12), bn>>2 selects tensor. V blocks (t==2)
// also accumulate column sums into sumv (atomicAdd; sumv pre-zeroed).
// ---------------------------------------------------------------------------
__global__ __launch_bounds__(256) void gemm_qkv(
    const float* __restrict__ A0, const float* __restrict__ A1, const float* __restrict__ A2,
    const u16* __restrict__ B,
    const float* __restrict__ b0, const float* __restrict__ b1, const float* __restrict__ b2,
    u16* __restrict__ o0, u16* __restrict__ o1, u16* __restrict__ o2,
    float* __restrict__ sumv)
{
    __shared__ __attribute__((aligned(16))) u16 As[128 * 64];
    __shared__ __attribute__((aligned(16))) u16 Bs[128 * 64];

    const int tid  = threadIdx.x;
    const int lane = tid & 63;
    const int w    = tid >> 6;
    const int bm   = blockIdx.x, bn = blockIdx.y;
    const int wm   = w >> 1, wn = w & 1;

    const int t = bn >> 2;
    const float* A = (t == 0) ? A0 : (t == 1) ? A1 : A2;
    const float* Ag = A + (size_t)bm * 128 * 512;
    const u16* Bg = B + (size_t)bn * 128 * 512;

    f32x4 acc[4][4];
#pragma unroll
    for (int m = 0; m < 4; ++m)
#pragma unroll
        for (int n = 0; n < 4; ++n) acc[m][n] = 0;

    const int swc = ((lane & 7) ^ (lane >> 3)) * 8;  // pre-swizzled source chunk (B)
    const int arow_g  = tid >> 4;   // row group 0..15 (row = p*16 + arow_g)
    const int alane16 = tid & 15;   // 16 threads per row, 16B each
    const int ach  = alane16 >> 1;  // k-chunk 0..7
    const int ahalf = alane16 & 1;  // half-chunk (4 elems)

    float4 av[8];
#pragma unroll
    for (int p = 0; p < 8; ++p)
        av[p] = *(const float4*)(Ag + (size_t)(p * 16 + arow_g) * 512 + alane16 * 4);

    for (int k0 = 0; k0 < 512; k0 += 64) {
        // ---- write staged A regs (f32 -> bf16, swizzled ushort4) ----
#pragma unroll
        for (int p = 0; p < 8; ++p) {
            int row = p * 16 + arow_g;
            ushort4 pk;
            pk.x = f2bf(av[p].x); pk.y = f2bf(av[p].y);
            pk.z = f2bf(av[p].z); pk.w = f2bf(av[p].w);
            *(ushort4*)(As + row * 64 + ((ach ^ (row & 7)) * 8) + ahalf * 4) = pk;
        }
        // ---- stage B (global_load_lds w16) ----
#pragma unroll
        for (int i = 0; i < 4; ++i) {
            int g = i * 4 + w;
            GLOAD_LDS(Bg + (size_t)(g * 8 + (lane >> 3)) * 512 + k0 + swc, Bs + g * 512);
        }
        __syncthreads();

        // ---- prefetch next K-tile's A into regs (hides under MFMA) ----
        if (k0 < 448) {
#pragma unroll
            for (int p = 0; p < 8; ++p)
                av[p] = *(const float4*)(Ag + (size_t)(p * 16 + arow_g) * 512 + (k0 + 64) + alane16 * 4);
        }

#pragma unroll
        for (int s = 0; s < 2; ++s) {
            bf16x8 af[4], bf[4];
            int c = s * 4 + (lane >> 4);
#pragma unroll
            for (int m = 0; m < 4; ++m) {
                int r = wm * 64 + m * 16 + (lane & 15);
                af[m] = *(const bf16x8*)(As + r * 64 + ((c ^ (r & 7)) * 8));
                int r2 = wn * 64 + m * 16 + (lane & 15);
                bf[m] = *(const bf16x8*)(Bs + r2 * 64 + ((c ^ (r2 & 7)) * 8));
            }
#pragma unroll
            for (int m = 0; m < 4; ++m)
#pragma unroll
                for (int n = 0; n < 4; ++n)
                    acc[m][n] = __builtin_amdgcn_mfma_f32_16x16x32_bf16(af[m], bf[n], acc[m][n], 0, 0, 0);
        }
        __syncthreads();
    }

    const float* bias = (t == 0) ? b0 : (t == 1) ? b1 : b2;
    u16* ob = (t == 0) ? o0 : (t == 1) ? o1 : o2;
    const int clbase = (bn & 3) * 128;

#pragma unroll
    for (int m = 0; m < 4; ++m) {
#pragma unroll
        for (int n = 0; n < 4; ++n) {
            int cl = clbase + wn * 64 + n * 16 + (lane & 15);
            float bb = bias[cl];
#pragma unroll
            for (int reg = 0; reg < 4; ++reg) {
                int row = bm * 128 + wm * 64 + m * 16 + (lane >> 4) * 4 + reg;
                ob[(size_t)row * 512 + cl] = f2bf(acc[m][n][reg] + bb);
            }
        }
    }

    // V-tensor blocks: column sums (this block's 128 rows) -> sumv[n][col]
    if (t == 2) {
        int nb = bm >> 4;                       // batch index (128 | 2048)
#pragma unroll
        for (int n = 0; n < 4; ++n) {
            float s = 0.f;
#pragma unroll
            for (int m = 0; m < 4; ++m)
#pragma unroll
                for (int reg = 0; reg < 4; ++reg) s += acc[m][n][reg];
            s += __shfl_xor(s, 16, 64);
            s += __shfl_xor(s, 32, 64);
            if (lane < 16) {
                int cl = clbase + wn * 64 + n * 16 + lane;
                atomicAdd(sumv + nb * 512 + cl, s);
            }
        }
    }
}

// ---------------------------------------------------------------------------
// Out projection: fo[8192,512] = A[8192,512] @ Wo^T + bo.  128x64 tile,
// grid (64,8) = 512 blocks (2/CU). 4 waves, wave tile 64x32 (4x2 frags).
// ---------------------------------------------------------------------------
__global__ __launch_bounds__(256) void gemm_o(
    const u16* __restrict__ A, const u16* __restrict__ B,
    const float* __restrict__ bias, float* __restrict__ fo)
{
    __shared__ __attribute__((aligned(16))) u16 As[128 * 64];
    __shared__ __attribute__((aligned(16))) u16 Bs[64 * 64];

    const int tid  = threadIdx.x;
    const int lane = tid & 63;
    const int w    = tid >> 6;
    const int bm   = blockIdx.x, bn = blockIdx.y;
    const int wm   = w >> 1, wn = w & 1;

    const u16* Ag = A + (size_t)bm * 128 * 512;
    const u16* Bg = B + (size_t)bn * 64 * 512;

    f32x4 acc[4][2];
#pragma unroll
    for (int m = 0; m < 4; ++m) { acc[m][0] = 0; acc[m][1] = 0; }

    const int swc = ((lane & 7) ^ (lane >> 3)) * 8;

    for (int k0 = 0; k0 < 512; k0 += 64) {
#pragma unroll
        for (int i = 0; i < 4; ++i) {
            int g = i * 4 + w;
            GLOAD_LDS(Ag + (size_t)(g * 8 + (lane >> 3)) * 512 + k0 + swc, As + g * 512);
        }
#pragma unroll
        for (int i = 0; i < 2; ++i) {
            int g = i * 4 + w;
            GLOAD_LDS(Bg + (size_t)(g * 8 + (lane >> 3)) * 512 + k0 + swc, Bs + g * 512);
        }
        __syncthreads();

#pragma unroll
        for (int s = 0; s < 2; ++s) {
            bf16x8 af[4], bf[2];
            int c = s * 4 + (lane >> 4);
#pragma unroll
            for (int m = 0; m < 4; ++m) {
                int r = wm * 64 + m * 16 + (lane & 15);
                af[m] = *(const bf16x8*)(As + r * 64 + ((c ^ (r & 7)) * 8));
            }
#pragma unroll
            for (int n = 0; n < 2; ++n) {
                int r2 = wn * 32 + n * 16 + (lane & 15);
                bf[n] = *(const bf16x8*)(Bs + r2 * 64 + ((c ^ (r2 & 7)) * 8));
            }
#pragma unroll
            for (int m = 0; m < 4; ++m)
#pragma unroll
                for (int n = 0; n < 2; ++n)
                    acc[m][n] = __builtin_amdgcn_mfma_f32_16x16x32_bf16(af[m], bf[n], acc[m][n], 0, 0, 0);
        }
        __syncthreads();
    }

#pragma unroll
    for (int m = 0; m < 4; ++m) {
#pragma unroll
        for (int n = 0; n < 2; ++n) {
            int cl = bn * 64 + wn * 32 + n * 16 + (lane & 15);
            float bb = bias[cl];
#pragma unroll
            for (int reg = 0; reg < 4; ++reg) {
                int row = bm * 128 + wm * 64 + m * 16 + (lane >> 4) * 4 + reg;
                fo[(size_t)row * 512 + cl] = acc[m][n][reg] + bb;
            }
        }
    }
}

// ---------------------------------------------------------------------------
// Fused windowed attention. One block = 32 query rows of one (n,h).
// Phases: stage Q/K/Vt -> MFMA scores -> softmax stats -> FILL-OUTSIDE
// (c-only rows, 86% of att bytes, starts before PV) -> A' f32 to LDS ->
// PV MFMA -> FILL-BAND (A'+c) -> oh epilogue.
// LDS: Qs/stats 4KB | A'/Ks 37.6KB | Vt [64][296] 37.9KB = 79.6KB (2/CU).
// ---------------------------------------------------------------------------
__global__ __launch_bounds__(256) void attn_kernel(
    const u16* __restrict__ qb, const u16* __restrict__ kb,
    const u16* __restrict__ vb, const int* __restrict__ mask,
    const float* __restrict__ sumv, float* __restrict__ att,
    u16* __restrict__ oh) {
    __shared__ __attribute__((aligned(16))) char lds[79616];
    u16*   Qs      = (u16*)lds;            // [32][64] bf16, chunk-swizzled
    float* stat_m  = (float*)lds;          // [32]  (aliases Qs after scores)
    float* stat_rd = (float*)(lds + 128);  // [32]
    float* stat_c  = (float*)(lds + 256);  // [32]
    float* red     = (float*)(lds + 384);  // [4][16]
    float* red2    = (float*)(lds + 640);  // [4][16]
    u16*   Ks      = (u16*)(lds + 4096);   // [288][64] bf16 (scores phase)
    float* Ab32    = (float*)(lds + 4096); // [32][292] f32 A' (after scores)
    u16*   Vt      = (u16*)(lds + 4096 + 37632); // [64][296] bf16 transposed

    const int tid  = threadIdx.x;
    const int lane = tid & 63;
    const int w    = tid >> 6;
    const int bid0 = blockIdx.x;
    const int bid  = (bid0 & 7) * 256 + (bid0 >> 3);   // XCD-chunked swizzle
    const int tile = bid & 63;
    const int h    = (bid >> 6) & 7;
    const int n    = bid >> 9;
    const int i0   = tile * 32;
    const int jlo  = max(0, i0 - 128);
    const int jend = min(2048, jlo + 288);
    const float scale = 0.04419417382415922f;  // 1/sqrt(512)

    const size_t base_nh = (size_t)n * 2048 * 512 + h * 64;
    const size_t rowbase = ((size_t)(n * 8 + h) * 2048 + i0) * 2048;
    const int lr = lane >> 3;              // row-in-group for staging
    const int swg = ((lane & 7) ^ lr) * 8; // source chunk (XOR swizzle)

    // ---- stage Qs [32][64] via global_load_lds (1 instr/wave) ----
    GLOAD_LDS(qb + base_nh + (size_t)(i0 + w * 8 + lr) * 512 + swg, Qs + w * 512);
    // ---- stage Ks [288][64] (rows >= 2048 clamped; masked later) ----
    for (int p = 0; p < 9; ++p) {
        int g = p * 4 + w;                 // row group 0..35
        int j = min(jlo + g * 8 + lr, 2047);
        GLOAD_LDS(kb + base_nh + (size_t)j * 512 + swg, Ks + g * 512);
    }
    // ---- stage Vt [64][296] = V^T; chunk-XOR write swizzle (2-way banks) ----
    for (int p = 0; p < 9; ++p) {
        int idx = p * 256 + tid;
        int jj = idx >> 3, ch = idx & 7;
        int j = jlo + jj;
        u16x8 tmp = {0, 0, 0, 0, 0, 0, 0, 0};
        if (j < 2048) tmp = *(const u16x8*)(vb + base_nh + (size_t)j * 512 + ch * 8);
        int jc = jj >> 3, jr = jj & 7;
        int pjc = (jc < 32) ? (jc ^ ch) : jc;
#pragma unroll
        for (int r = 0; r < 8; ++r)
            Vt[(ch * 8 + r) * 296 + pjc * 8 + jr] = tmp[r];
    }
    __syncthreads();

    // ---- scores: S[32][288] = Q . K^T, wave -> 16 rows x 144 cols ----
    const int rbase = (w & 1) * 16;
    const int cbase = (w >> 1) * 144;
    f32x4 acc[9];
#pragma unroll
    for (int f = 0; f < 9; ++f) acc[f] = 0;

    bf16x8 aq[2];
    {
        int r = rbase + (lane & 15);
#pragma unroll
        for (int ks = 0; ks < 2; ++ks) {
            int kc = ks * 4 + (lane >> 4);
            aq[ks] = *(const bf16x8*)(Qs + r * 64 + ((kc ^ (r & 7)) * 8));
        }
    }
#pragma unroll
    for (int f = 0; f < 9; ++f) {
        int jj = cbase + f * 16 + (lane & 15);
#pragma unroll
        for (int ks = 0; ks < 2; ++ks) {
            int kc = ks * 4 + (lane >> 4);
            bf16x8 bk_ = *(const bf16x8*)(Ks + jj * 64 + ((kc ^ (jj & 7)) * 8));
            acc[f] = __builtin_amdgcn_mfma_f32_16x16x32_bf16(aq[ks], bk_, acc[f], 0, 0, 0);
        }
    }
    __syncthreads();   // Qs/Ks reads done; stats/A' may alias

    // ---- pass 1: logits + per-row max ----
    const int rowg = (lane >> 4) * 4;
    f32x4 lv[9];
    float mx[4] = {-__builtin_inff(), -__builtin_inff(), -__builtin_inff(), -__builtin_inff()};
#pragma unroll
    for (int f = 0; f < 9; ++f) {
        int jj = cbase + f * 16 + (lane & 15);
        int j = jlo + jj;
        int mk = (j < 2048) ? mask[n * 2048 + j] : 0;
#pragma unroll
        for (int reg = 0; reg < 4; ++reg) {
            int i = i0 + rbase + rowg + reg;
            bool inw = (j >= i - 128) && (j <= i + 128) && (j < 2048);
            float val = (inw && mk != 0) ? acc[f][reg] * scale : -__builtin_inff();
            lv[f][reg] = val;
            mx[reg] = fmaxf(mx[reg], val);
        }
    }
#pragma unroll
    for (int mskk = 1; mskk < 16; mskk <<= 1)
#pragma unroll
        for (int reg = 0; reg < 4; ++reg)
            mx[reg] = fmaxf(mx[reg], __shfl_xor(mx[reg], mskk, 64));
    if ((lane & 15) == 0) {
#pragma unroll
        for (int reg = 0; reg < 4; ++reg) red[w * 16 + rowg + reg] = mx[reg];
    }
    __syncthreads();
    if (tid < 32) {
        int r = tid;
        int wa = (r < 16) ? 0 : 1, rr = r & 15;
        stat_m[r] = fmaxf(fmaxf(red[wa * 16 + rr], red[(wa + 2) * 16 + rr]), 0.0f);
    }
    __syncthreads();

    // ---- pass 2: denom ----
    float m4[4];
#pragma unroll
    for (int reg = 0; reg < 4; ++reg) m4[reg] = stat_m[rbase + rowg + reg];
    float sm[4] = {0, 0, 0, 0};
#pragma unroll
    for (int f = 0; f < 9; ++f)
#pragma unroll
        for (int reg = 0; reg < 4; ++reg)
            sm[reg] += __expf(lv[f][reg] - m4[reg]);
#pragma unroll
    for (int mskk = 1; mskk < 16; mskk <<= 1)
#pragma unroll
        for (int reg = 0; reg < 4; ++reg)
            sm[reg] += __shfl_xor(sm[reg], mskk, 64);
    if ((lane & 15) == 0) {
#pragma unroll
        for (int reg = 0; reg < 4; ++reg) red2[w * 16 + rowg + reg] = sm[reg];
    }
    __syncthreads();
    if (tid < 32) {
        int r = tid, gi = i0 + r;
        int wa = (r < 16) ? 0 : 1, rr = r & 15;
        float s = red2[wa * 16 + rr] + red2[(wa + 2) * 16 + rr];
        int lo = max(0, gi - 128), hi = min(2048, gi + 129);
        float em = __expf(-stat_m[r]);
        float denom = s + (float)(2048 - (hi - lo)) * em;
        float rd = 1.0f / denom;
        stat_rd[r] = rd;
        stat_c[r] = em * rd;
    }
    __syncthreads();

    // ---- FILL-OUTSIDE: stream c-only f32x4 segments (86% of att bytes);
    //      starts before pass3/PV so stores drain under the MFMA compute ----
    {
        int j4lo = jlo >> 2, j4end = jend >> 2;
        for (int idx = tid; idx < 32 * 512; idx += 256) {
            int r = idx >> 9, j4 = idx & 511;
            if (j4 >= j4lo && j4 < j4end) continue;
            float c = stat_c[r];
            f32x4 v = {c, c, c, c};
            __builtin_nontemporal_store(v, (f32x4*)(att + rowbase + (size_t)r * 2048 + j4 * 4));
        }
    }

    // ---- pass 3: A' = (att - c) f32 -> LDS [32][292] ----
    float rd4[4], c4[4];
#pragma unroll
    for (int reg = 0; reg < 4; ++reg) {
        rd4[reg] = stat_rd[rbase + rowg + reg];
        c4[reg] = stat_c[rbase + rowg + reg];
    }
#pragma unroll
    for (int f = 0; f < 9; ++f) {
        int jj = cbase + f * 16 + (lane & 15);
        int j = jlo + jj;
#pragma unroll
        for (int reg = 0; reg < 4; ++reg) {
            int it = rbase + rowg + reg;
            int i = i0 + it;
            bool inw = (j >= i - 128) && (j <= i + 128) && (j < 2048);
            float e = __expf(lv[f][reg] - m4[reg]);
            Ab32[it * 292 + jj] = inw ? (e * rd4[reg] - c4[reg]) : 0.0f;
        }
    }
    __syncthreads();

    // ---- PV: out[32][64] = A'[32][288] @ V[288][64] (via Vt) ----
    const int rb2 = (w & 1) * 16;
    const int db  = (w >> 1) * 32;
    f32x4 po[2];
    po[0] = 0; po[1] = 0;
#pragma unroll
    for (int ks = 0; ks < 9; ++ks) {
        int kc = ks * 4 + (lane >> 4);
        int it = rb2 + (lane & 15);
        const float* ap = Ab32 + it * 292 + kc * 8;
        float4 alo = *(const float4*)(ap);
        float4 ahi = *(const float4*)(ap + 4);
        bf16x8 af;
        af[0] = (__bf16)alo.x; af[1] = (__bf16)alo.y;
        af[2] = (__bf16)alo.z; af[3] = (__bf16)alo.w;
        af[4] = (__bf16)ahi.x; af[5] = (__bf16)ahi.y;
        af[6] = (__bf16)ahi.z; af[7] = (__bf16)ahi.w;
#pragma unroll
        for (int f = 0; f < 2; ++f) {
            int d = db + f * 16 + (lane & 15);
            int phys = (kc < 32) ? (kc ^ (d >> 3)) : kc;
            bf16x8 bv_ = *(const bf16x8*)(Vt + d * 296 + phys * 8);
            po[f] = __builtin_amdgcn_mfma_f32_16x16x32_bf16(af, bv_, po[f], 0, 0, 0);
        }
    }

    // ---- FILL-BAND: att[j] = A' + c over [jlo, jend), f32x4 NT ----
    {
        int nseg = (jend - jlo) >> 2;      // band f32x4 segments per row (<=72)
        for (int idx = tid; idx < 32 * 72; idx += 256) {
            int r = idx / 72, q = idx % 72;
            if (q >= nseg) continue;
            float c = stat_c[r];
            const float* ap = Ab32 + r * 292 + q * 4;
            f32x4 v = {ap[0] + c, ap[1] + c, ap[2] + c, ap[3] + c};
            __builtin_nontemporal_store(v, (f32x4*)(att + rowbase + (size_t)r * 2048 + jlo + q * 4));
        }
    }

    // ---- oh epilogue (+ c*sumv correction) ----
    {
        const float* svp = sumv + (size_t)n * 512 + h * 64;
#pragma unroll
        for (int f = 0; f < 2; ++f) {
            int d = db + f * 16 + (lane & 15);
            float sv = svp[d];
#pragma unroll
            for (int reg = 0; reg < 4; ++reg) {
                int it = rb2 + rowg + reg;
                float val = po[f][reg] + stat_c[it] * sv;
                oh[base_nh + (size_t)(i0 + it) * 512 + d] = f2bf(val);
            }
        }
    }
}

// ---------------------------------------------------------------------------
extern "C" void kernel_launch(void* const* d_in, const int* in_sizes, int n_in,
                              void* d_out, int out_size, void* d_ws, size_t ws_size,
                              hipStream_t stream) {
    const float* value = (const float*)d_in[0];
    const float* key_  = (const float*)d_in[1];
    const float* query = (const float*)d_in[2];
    const int*   mask  = (const int*)d_in[3];
    const float* Wv = (const float*)d_in[4];
    const float* bv = (const float*)d_in[5];
    const float* Wk = (const float*)d_in[6];
    const float* bk = (const float*)d_in[7];
    const float* Wq = (const float*)d_in[8];
    const float* bq = (const float*)d_in[9];
    const float* Wo = (const float*)d_in[10];
    const float* bo = (const float*)d_in[11];

    char* ws = (char*)d_ws;
    size_t off = 0;
    auto carve = [&](size_t bytes) -> char* {
        char* p = ws + off;
        off += (bytes + 255) & ~(size_t)255;
        return p;
    };
    const size_t XB = (size_t)8192 * 512 * 2;   // bf16 [8192,512]
    const size_t WB = (size_t)512 * 512 * 2;    // bf16 [512,512]
    u16* wqkv = (u16*)carve(3 * WB);            // [1536,512]: Wq rows, Wk, Wv
    u16* wob  = (u16*)carve(WB);
    u16* qb   = (u16*)carve(XB);
    u16* kb   = (u16*)carve(XB);
    u16* vb2  = (u16*)carve(XB);
    u16* ohb  = (u16*)carve(XB);
    float* sumv = (float*)carve(2048 * sizeof(float));

    CvtWArgs ca;
    ca.src[0] = Wq; ca.dst[0] = wqkv;
    ca.src[1] = Wk; ca.dst[1] = wqkv + (size_t)512 * 512;
    ca.src[2] = Wv; ca.dst[2] = wqkv + (size_t)1024 * 512;
    ca.src[3] = Wo; ca.dst[3] = wob;

    cvt_w<<<dim3(1024), 256, 0, stream>>>(ca, sumv);
    gemm_qkv<<<dim3(64, 12), 256, 0, stream>>>(
        query, key_, value, wqkv, bq, bk, bv, qb, kb, vb2, sumv);

    float* att = (float*)d_out + (size_t)4 * 2048 * 512;
    attn_kernel<<<dim3(2048), 256, 0, stream>>>(qb, kb, vb2, mask, sumv, att, ohb);
    gemm_o<<<dim3(64, 8), 256, 0, stream>>>(ohb, wob, bo, (float*)d_out);
}